// Round 8
// baseline (602.878 us; speedup 1.0000x reference)
//
#include <hip/hip_runtime.h>
#include <hip/hip_bf16.h>

#define DD 128
#define RR 8
#define KK 1152      // RGCN composite K = 128 + 8*128
#define SCAN_CHUNK 2048
#define KSPLIT 8
#define KP 4096      // padded sim K
#define ROWS 16      // fused-layer rows per block
#define BK2 64       // fused-layer K-step

typedef _Float16 h8 __attribute__((ext_vector_type(8)));
typedef _Float16 h4 __attribute__((ext_vector_type(4)));
typedef float f4 __attribute__((ext_vector_type(4)));

__device__ __forceinline__ void gload16(const _Float16* g, _Float16* l) {
  __builtin_amdgcn_global_load_lds(
      (const __attribute__((address_space(1))) void*)g,
      (__attribute__((address_space(3))) void*)l, 16, 0, 0);
}

// ---------------- count edges per (dst, rel) and in-degree ----------------
__global__ __launch_bounds__(256) void count_k(const int* __restrict__ edst,
    const int* __restrict__ etyp, int* __restrict__ cnt, int* __restrict__ deg, int E) {
  int i = blockIdx.x * 256 + threadIdx.x;
  if (i < E) {
    int d = edst[i];
    atomicAdd(&cnt[d * RR + etyp[i]], 1);
    atomicAdd(&deg[d], 1);
  }
}

// ---------------- 3-phase exclusive scan of cnt -> off ----------------
__global__ __launch_bounds__(256) void scan_a(const int* __restrict__ cnt,
    int* __restrict__ off, int* __restrict__ bsum, int n) {
  __shared__ int red[256];
  int base = blockIdx.x * SCAN_CHUNK + threadIdx.x * 8;
  int v[8];
  int s = 0;
#pragma unroll
  for (int i = 0; i < 8; ++i) {
    int idx = base + i;
    v[i] = s;
    s += (idx < n) ? cnt[idx] : 0;
  }
  red[threadIdx.x] = s;
  __syncthreads();
  for (int o = 1; o < 256; o <<= 1) {
    int t = (threadIdx.x >= o) ? red[threadIdx.x - o] : 0;
    __syncthreads();
    red[threadIdx.x] += t;
    __syncthreads();
  }
  int pre = (threadIdx.x > 0) ? red[threadIdx.x - 1] : 0;
#pragma unroll
  for (int i = 0; i < 8; ++i) {
    int idx = base + i;
    if (idx < n) off[idx] = v[i] + pre;
  }
  if (threadIdx.x == 255) bsum[blockIdx.x] = red[255];
}

__global__ void scan_b(int* __restrict__ bsum, int nb) {
  if (threadIdx.x == 0) {
    int s = 0;
    for (int i = 0; i < nb; ++i) { int t = bsum[i]; bsum[i] = s; s += t; }
  }
}

__global__ __launch_bounds__(256) void scan_c(int* __restrict__ off,
    const int* __restrict__ bsum, int n) {
  int i = blockIdx.x * 256 + threadIdx.x;
  if (i < n) off[i] += bsum[i >> 11];
}

// ---------------- fill CSR ----------------
__global__ __launch_bounds__(256) void fill_k(const int* __restrict__ esrc,
    const int* __restrict__ edst, const int* __restrict__ etyp,
    int* __restrict__ cur, int* __restrict__ eidx, int E) {
  int e = blockIdx.x * 256 + threadIdx.x;
  if (e < E) {
    int seg = edst[e] * RR + etyp[e];
    int p = atomicAdd(&cur[seg], 1);
    eidx[p] = esrc[e];
  }
}

// ---------------- fp32 -> f16 convert of x ----------------
__global__ __launch_bounds__(256) void convx_k(const float* __restrict__ x,
    _Float16* __restrict__ xh, int n4) {
  int i = blockIdx.x * 256 + threadIdx.x;
  if (i < n4) {
    float4 v = *(const float4*)(x + (size_t)i * 4);
    h4 o = {(_Float16)v.x, (_Float16)v.y, (_Float16)v.z, (_Float16)v.w};
    *(h4*)(xh + (size_t)i * 4) = o;
  }
}

// ---------------- build transposed f16 weights WT[n][k] ----------------
__global__ __launch_bounds__(256) void convw_k(const float* __restrict__ Ws,
    const float* __restrict__ Wr, _Float16* __restrict__ WT) {
  int gid = blockIdx.x * 256 + threadIdx.x;
  if (gid < DD * KK) {
    int n = gid / KK, k = gid % KK;
    float v = (k < DD) ? Ws[(size_t)k * DD + n] : Wr[(size_t)(k - DD) * DD + n];
    WT[gid] = (_Float16)v;
  }
}

// ---------------- sim row convert + fused rowsum (body) ----------------
__device__ __forceinline__ void convsim_body(const float* __restrict__ sim,
    const int* __restrict__ mri, const float* __restrict__ maskf,
    _Float16* __restrict__ simh, float* __restrict__ rs, int nd, int i,
    float* red) {
  const float* row = sim + (size_t)mri[i] * nd;
  float acc = 0.f;
  for (int c4 = threadIdx.x; c4 < KP / 4; c4 += 256) {
    int c = c4 * 4;
    float4 v = make_float4(0.f, 0.f, 0.f, 0.f);
    if (c < nd) {
      v = *(const float4*)(row + c);
      float4 mk = *(const float4*)(maskf + c);
      acc += v.x * mk.x + v.y * mk.y + v.z * mk.z + v.w * mk.w;
    }
    h4 o = {(_Float16)v.x, (_Float16)v.y, (_Float16)v.z, (_Float16)v.w};
    *(h4*)(simh + (size_t)i * KP + c) = o;
  }
  red[threadIdx.x] = acc;
  __syncthreads();
  for (int o = 128; o > 0; o >>= 1) {
    if (threadIdx.x < o) red[threadIdx.x] += red[threadIdx.x + o];
    __syncthreads();
  }
  if (threadIdx.x == 0) rs[i] = red[0] + 1e-9f;
}

// ---------------- FUSED RGCN layer v3 ------------------------------------
// 16 rows/block. Phase G: gather CSR segment means ONCE into swizzled LDS
// msgT[16][1152] (self rows k<128 + 8 rels). Phase M: standard MFMA GEMM,
// A from msgT, B reg-staged from L2-resident WT (issue-early/write-late).
// 53 KB LDS -> 3 blocks/CU: one block's G hides under other blocks' M.
template <bool RELU, bool F16OUT, bool COSIM>
__global__ __launch_bounds__(256) void fused_layer(
    const _Float16* __restrict__ hfeat, const int* __restrict__ off,
    const int* __restrict__ eidx, const _Float16* __restrict__ WT,
    void* __restrict__ outv, int nN, int E, int nfused,
    const float* __restrict__ sim, const int* __restrict__ mri,
    const float* __restrict__ maskf, _Float16* __restrict__ simh,
    float* __restrict__ rs, int nd) {
  __shared__ char smem[ROWS * KK * 2 + 128 * BK2 * 2];  // 36864 + 16384 = 53248
  if (COSIM && (int)blockIdx.x >= nfused) {
    convsim_body(sim, mri, maskf, simh, rs, nd, blockIdx.x - nfused,
                 (float*)smem);
    return;
  }
  _Float16* msgT = (_Float16*)smem;                       // [16][1152] chunk-swizzled
  _Float16* Bs   = (_Float16*)(smem + ROWS * KK * 2);     // [128][64] chunk-swizzled

  const int t = threadIdx.x;
  const int row0 = blockIdx.x * ROWS;

  // ---- B(0) -> regs early (independent of G; hides under gather) ----
  const int bn = t >> 1;                 // 0..127 (WT row = out col)
  const int bc0 = (t & 1) * 4;           // chunk 0..3 or 4..7
  const _Float16* wrow = WT + (size_t)bn * KK;
  uint4 breg[4];
#pragma unroll
  for (int j = 0; j < 4; ++j)
    breg[j] = *(const uint4*)(wrow + (size_t)(bc0 + j) * 8);

  // ---- G1: self rows -> msgT k in [0,128) ----
  {
    int row = t >> 4, c = t & 15;        // coalesced global read
    int gm = row0 + row; if (gm >= nN) gm = nN - 1;
    uint4 v = *(const uint4*)(hfeat + (size_t)gm * DD + c * 8);
    int csw = (c & ~7) | ((c & 7) ^ (row & 7));
    *(uint4*)&msgT[row * KK + csw * 8] = v;
  }
  // ---- G2: relation means -> msgT k in [128,1152) ----
  {
    const int row = t & 15;              // LDS-write-uniform mapping
    const int r = (t >> 4) & 7;
    const int half = t >> 7;             // 64-col half
    int gm = row0 + row; if (gm >= nN) gm = nN - 1;
    const int gseg = gm * RR + r;
    const int b = off[gseg];
    const int e = (gseg + 1 < nN * RR) ? off[gseg + 1] : E;
    const int n = e - b;
    h8 a[8];
#pragma unroll
    for (int j = 0; j < 8; ++j) a[j] = (h8){0, 0, 0, 0, 0, 0, 0, 0};
    int sNext = (b < e) ? eidx[b] : 0;
    for (int i = b; i < e; ++i) {
      int s = sNext;
      if (i + 1 < e) sNext = eidx[i + 1];
      const _Float16* hp = hfeat + (size_t)s * DD + half * 64;
#pragma unroll
      for (int j = 0; j < 8; ++j) a[j] += *(const h8*)(hp + j * 8);
    }
    const _Float16 ic = (_Float16)((n > 0) ? 1.0f / (float)n : 0.0f);
    const int cb = 16 + r * 16 + half * 8;   // chunk base (8-aligned)
#pragma unroll
    for (int j = 0; j < 8; ++j) {
      h8 m = a[j] * ic;
      int c = cb + j;
      int csw = (c & ~7) | ((c & 7) ^ (row & 7));
      *(h8*)&msgT[row * KK + csw * 8] = m;
    }
  }
  __syncthreads();                       // msgT complete
  // write B(0) to LDS
#pragma unroll
  for (int j = 0; j < 4; ++j) {
    int c = bc0 + j, csw = c ^ (bn & 7);
    *(uint4*)&Bs[bn * BK2 + csw * 8] = breg[j];
  }
  __syncthreads();                       // B(0) visible

  const int lane = t & 63, w = t >> 6;
  const int lr = lane & 15, lg = lane >> 4;
  f4 acc[2];
  acc[0] = (f4){0.f, 0.f, 0.f, 0.f};
  acc[1] = (f4){0.f, 0.f, 0.f, 0.f};

  const int nsteps = KK / BK2;           // 18
  for (int ts = 0; ts < nsteps; ++ts) {
    if (ts + 1 < nsteps) {               // issue next B early
#pragma unroll
      for (int j = 0; j < 4; ++j)
        breg[j] = *(const uint4*)(wrow + (size_t)(ts + 1) * BK2 +
                                  (size_t)(bc0 + j) * 8);
    }
#pragma unroll
    for (int s = 0; s < 2; ++s) {
      int ca = ts * 8 + s * 4 + lg;      // A chunk (group-local XOR safe)
      int casw = (ca & ~7) | ((ca & 7) ^ (lr & 7));
      h8 af = *(const h8*)&msgT[lr * KK + casw * 8];
#pragma unroll
      for (int nf = 0; nf < 2; ++nf) {
        int nc = w * 32 + nf * 16 + lr;
        int cbw = (s * 4 + lg) ^ (nc & 7);
        h8 bf = *(const h8*)&Bs[nc * BK2 + cbw * 8];
        acc[nf] = __builtin_amdgcn_mfma_f32_16x16x32_f16(af, bf, acc[nf], 0, 0, 0);
      }
    }
    __syncthreads();                     // all waves done reading B(ts)
    if (ts + 1 < nsteps) {
#pragma unroll
      for (int j = 0; j < 4; ++j) {
        int c = bc0 + j, csw = c ^ (bn & 7);
        *(uint4*)&Bs[bn * BK2 + csw * 8] = breg[j];
      }
    }
    __syncthreads();                     // B(ts+1) visible
  }

  // epilogue: C/D layout col=lane&15, row=(lane>>4)*4+reg
#pragma unroll
  for (int nf = 0; nf < 2; ++nf) {
#pragma unroll
    for (int j = 0; j < 4; ++j) {
      int row = row0 + lg * 4 + j;
      if (row < nN) {
        int col = w * 32 + nf * 16 + lr;
        float v = acc[nf][j];
        if (RELU) v = fmaxf(v, 0.f);
        if (F16OUT)
          ((_Float16*)outv)[(size_t)row * DD + col] = (_Float16)v;
        else
          ((float*)outv)[(size_t)row * DD + col] = v;
      }
    }
  }
}

// ---------------- maskf scatter: maskf[mri[i]] = 1 ----------------
__global__ __launch_bounds__(256) void maskset_k(const int* __restrict__ mri,
    float* __restrict__ maskf, int nd) {
  int i = blockIdx.x * 256 + threadIdx.x;
  if (i < nd) maskf[mri[i]] = 1.0f;
}

// ---------------- gather disease rows (fp32 hbp) + scatter f16 into hbs ----------------
__global__ __launch_bounds__(256) void gather2_k(const float* __restrict__ h2,
    const int* __restrict__ bli, const int* __restrict__ mri,
    float* __restrict__ hbp, _Float16* __restrict__ hbs, int nd) {
  int gid = blockIdx.x * 256 + threadIdx.x;
  int i = gid >> 5, q = gid & 31;
  if (i < nd) {
    float4 v = *(const float4*)(h2 + (size_t)bli[i] * DD + q * 4);
    *(float4*)(hbp + (size_t)i * DD + q * 4) = v;
    h4 o = {(_Float16)v.x, (_Float16)v.y, (_Float16)v.z, (_Float16)v.w};
    *(h4*)(hbs + (size_t)mri[i] * DD + q * 4) = o;
  }
}

// ---------------- transpose hbs[KP][128] -> hbsT[128][KP] ----------------
__global__ __launch_bounds__(256) void transpose_k(const _Float16* __restrict__ hbs,
    _Float16* __restrict__ hbsT) {
  __shared__ _Float16 tile[64][72];
  int r0 = blockIdx.x * 64, c0 = blockIdx.y * 64;
  int t = threadIdx.x;
  int r = t >> 2, cs = (t & 3) * 16;
  *(h8*)&tile[r][cs]     = *(const h8*)(hbs + (size_t)(r0 + r) * DD + c0 + cs);
  *(h8*)&tile[r][cs + 8] = *(const h8*)(hbs + (size_t)(r0 + r) * DD + c0 + cs + 8);
  __syncthreads();
  int n = t >> 2, rs2 = (t & 3) * 16;
  h8 o0, o1;
#pragma unroll
  for (int j = 0; j < 8; ++j) {
    o0[j] = tile[rs2 + j][n];
    o1[j] = tile[rs2 + 8 + j][n];
  }
  *(h8*)(hbsT + (size_t)(c0 + n) * KP + r0 + rs2)     = o0;
  *(h8*)(hbsT + (size_t)(c0 + n) * KP + r0 + rs2 + 8) = o1;
}

// ---------------- sim MFMA GEMM: hs_part[ky] = simh[:, kchunk] @ hbsT^T ----------------
__global__ __launch_bounds__(256) void sim_mfma(const _Float16* __restrict__ simh,
    const _Float16* __restrict__ hbsT, float* __restrict__ hs_part, int nd) {
  __shared__ _Float16 Ab[2][64 * 64];
  __shared__ _Float16 Bb[2][128 * 64];
  const int t = threadIdx.x;
  const int lane = t & 63, w = t >> 6;
  const int row0 = blockIdx.x * 64;
  const int kb0 = blockIdx.y * (KP / KSPLIT);
  const int wm = w >> 1, wn = w & 1;
  const int lr = lane & 15, lg = lane >> 4;

  f4 acc[2][4];
#pragma unroll
  for (int mi = 0; mi < 2; ++mi)
#pragma unroll
    for (int ni = 0; ni < 4; ++ni) acc[mi][ni] = (f4){0.f, 0.f, 0.f, 0.f};

  const _Float16* pA[2];
  int ldsA[2];
#pragma unroll
  for (int j = 0; j < 2; ++j) {
    int q = j * 256 + w * 64 + lane;
    int row = q >> 3;
    int gck = (q & 7) ^ (row & 7);
    int m = row0 + row; if (m >= nd) m = nd - 1;
    pA[j] = simh + (size_t)m * KP + kb0 + gck * 8;
    ldsA[j] = (j * 256 + w * 64) * 8;
  }
  const _Float16* pB[4];
  int ldsB[4];
#pragma unroll
  for (int i = 0; i < 4; ++i) {
    int q = i * 256 + w * 64 + lane;
    int n = q >> 3;
    int gck = (q & 7) ^ (n & 7);
    pB[i] = hbsT + (size_t)n * KP + kb0 + gck * 8;
    ldsB[i] = (i * 256 + w * 64) * 8;
  }

  const int nsteps = (KP / KSPLIT) / 64;  // 8
#pragma unroll
  for (int j = 0; j < 2; ++j) gload16(pA[j], &Ab[0][ldsA[j]]);
#pragma unroll
  for (int i = 0; i < 4; ++i) gload16(pB[i], &Bb[0][ldsB[i]]);
  asm volatile("s_waitcnt vmcnt(0)" ::: "memory");
  __syncthreads();

  for (int ts = 0; ts < nsteps; ++ts) {
    const int cur = ts & 1;
    if (ts + 1 < nsteps) {
      const int kk = (ts + 1) * 64;
      const int nxt = cur ^ 1;
#pragma unroll
      for (int j = 0; j < 2; ++j) gload16(pA[j] + kk, &Ab[nxt][ldsA[j]]);
#pragma unroll
      for (int i = 0; i < 4; ++i) gload16(pB[i] + kk, &Bb[nxt][ldsB[i]]);
    }
#pragma unroll
    for (int s = 0; s < 2; ++s) {
      h8 af[2], bf[4];
#pragma unroll
      for (int mi = 0; mi < 2; ++mi) {
        int r = wm * 32 + mi * 16 + lr;
        af[mi] = *(const h8*)&Ab[cur][r * 64 + (((s * 4 + lg) ^ (r & 7)) << 3)];
      }
#pragma unroll
      for (int ni = 0; ni < 4; ++ni) {
        int n = wn * 64 + ni * 16 + lr;
        bf[ni] = *(const h8*)&Bb[cur][n * 64 + (((s * 4 + lg) ^ (n & 7)) << 3)];
      }
#pragma unroll
      for (int mi = 0; mi < 2; ++mi)
#pragma unroll
        for (int ni = 0; ni < 4; ++ni)
          acc[mi][ni] = __builtin_amdgcn_mfma_f32_16x16x32_f16(
              af[mi], bf[ni], acc[mi][ni], 0, 0, 0);
    }
    asm volatile("s_waitcnt vmcnt(0)" ::: "memory");
    __syncthreads();
  }

  float* dst = hs_part + (size_t)blockIdx.y * nd * DD;
#pragma unroll
  for (int mi = 0; mi < 2; ++mi) {
#pragma unroll
    for (int j = 0; j < 4; ++j) {
      int row = row0 + wm * 32 + mi * 16 + lg * 4 + j;
      if (row < nd) {
#pragma unroll
        for (int ni = 0; ni < 4; ++ni) {
          int col = wn * 64 + ni * 16 + lr;
          dst[(size_t)row * DD + col] = acc[mi][ni][j];
        }
      }
    }
  }
}

__global__ __launch_bounds__(256) void reduce_k(const float* __restrict__ part,
    float* __restrict__ hs, int n) {
  int i = blockIdx.x * 256 + threadIdx.x;
  if (i < n) {
    float4 s = make_float4(0.f, 0.f, 0.f, 0.f);
#pragma unroll
    for (int p = 0; p < KSPLIT; ++p) {
      float4 v = *(const float4*)(part + (size_t)p * n * 4 + i * 4);
      s.x += v.x; s.y += v.y; s.z += v.z; s.w += v.w;
    }
    *(float4*)(hs + (size_t)i * 4) = s;
  }
}

// ---------------- final blend into d_out at disease rows ----------------
__global__ __launch_bounds__(256) void final_k(const float* __restrict__ hs,
    const float* __restrict__ hbp, const float* __restrict__ rs,
    const int* __restrict__ bli, const int* __restrict__ deg,
    float* __restrict__ out, int nd) {
  int gid = blockIdx.x * 256 + threadIdx.x;
  int i = gid >> 5, q = gid & 31;
  if (i < nd) {
    int g = bli[i];
    float cg = 0.7f * expf(-0.7f * (float)deg[g]) + 0.2f;
    float inv = 1.0f / rs[i];
    float4 s = *(const float4*)(hs + (size_t)i * DD + q * 4);
    float4 b = *(const float4*)(hbp + (size_t)i * DD + q * 4);
    float4 o;
    o.x = cg * (s.x * inv) + (1.f - cg) * b.x;
    o.y = cg * (s.y * inv) + (1.f - cg) * b.y;
    o.z = cg * (s.z * inv) + (1.f - cg) * b.z;
    o.w = cg * (s.w * inv) + (1.f - cg) * b.w;
    *(float4*)(out + (size_t)g * DD + q * 4) = o;
  }
}

extern "C" void kernel_launch(void* const* d_in, const int* in_sizes, int n_in,
                              void* d_out, int out_size, void* d_ws, size_t ws_size,
                              hipStream_t stream) {
  const float* x   = (const float*)d_in[0];
  const float* sim = (const float*)d_in[1];
  const float* W1s = (const float*)d_in[2];
  const float* W1r = (const float*)d_in[3];
  const float* W2s = (const float*)d_in[4];
  const float* W2r = (const float*)d_in[5];
  const int* esrc  = (const int*)d_in[6];
  const int* edst  = (const int*)d_in[7];
  const int* etyp  = (const int*)d_in[8];
  const int* bli   = (const int*)d_in[9];
  const int* mri   = (const int*)d_in[10];
  const int N  = in_sizes[0] / DD;
  const int E  = in_sizes[6];
  const int ND = in_sizes[9];
  const int NR = N * RR;
  float* out = (float*)d_out;

  // workspace carve-up (~80 MB, msg eliminated)
  char* w = (char*)d_ws;
  _Float16* xh   = (_Float16*)w; w += (size_t)N * DD * sizeof(_Float16);
  _Float16* h1h  = (_Float16*)w; w += (size_t)N * DD * sizeof(_Float16);
  _Float16* WT1  = (_Float16*)w; w += (size_t)DD * KK * sizeof(_Float16);
  _Float16* WT2  = (_Float16*)w; w += (size_t)DD * KK * sizeof(_Float16);
  _Float16* simh = (_Float16*)w; w += (size_t)ND * KP * sizeof(_Float16);
  _Float16* hbs  = (_Float16*)w; w += (size_t)KP * DD * sizeof(_Float16);
  _Float16* hbsT = (_Float16*)w; w += (size_t)DD * KP * sizeof(_Float16);
  float* hs_part = (float*)w; w += (size_t)KSPLIT * ND * DD * sizeof(float);
  float* hbp   = (float*)w; w += (size_t)ND * DD * sizeof(float);
  float* hs    = (float*)w; w += (size_t)ND * DD * sizeof(float);
  float* maskf = (float*)w; w += (size_t)KP * sizeof(float);
  int* cnt  = (int*)w; w += (size_t)NR * sizeof(int);
  int* deg  = (int*)w; w += (size_t)N * sizeof(int);
  int* off  = (int*)w; w += (size_t)NR * sizeof(int);
  int* cur  = (int*)w; w += (size_t)NR * sizeof(int);
  int* eidx = (int*)w; w += (size_t)E * sizeof(int);
  int* bsum = (int*)w; w += 1024 * sizeof(int);
  float* rs = (float*)w; w += (size_t)ND * sizeof(float);

  // ---- CSR build ----
  hipMemsetAsync(cnt, 0, (size_t)(NR + N) * sizeof(int), stream);
  count_k<<<(E + 255) / 256, 256, 0, stream>>>(edst, etyp, cnt, deg, E);
  int nblk = (NR + SCAN_CHUNK - 1) / SCAN_CHUNK;
  scan_a<<<nblk, 256, 0, stream>>>(cnt, off, bsum, NR);
  scan_b<<<1, 256, 0, stream>>>(bsum, nblk);
  scan_c<<<(NR + 255) / 256, 256, 0, stream>>>(off, bsum, NR);
  hipMemcpyAsync(cur, off, (size_t)NR * sizeof(int), hipMemcpyDeviceToDevice, stream);
  fill_k<<<(E + 255) / 256, 256, 0, stream>>>(esrc, edst, etyp, cur, eidx, E);

  // ---- f16 conversions + sim mask prep + hbs clear ----
  convx_k<<<(N * DD / 4 + 255) / 256, 256, 0, stream>>>(x, xh, N * DD / 4);
  convw_k<<<(DD * KK + 255) / 256, 256, 0, stream>>>(W1s, W1r, WT1);
  convw_k<<<(DD * KK + 255) / 256, 256, 0, stream>>>(W2s, W2r, WT2);
  hipMemsetAsync(maskf, 0, (size_t)KP * sizeof(float), stream);
  maskset_k<<<(ND + 255) / 256, 256, 0, stream>>>(mri, maskf, ND);
  hipMemsetAsync(hbs, 0, (size_t)KP * DD * sizeof(_Float16), stream);

  // ---- fused layer 1 (+ co-scheduled convsim) ----
  const int nfused = (N + ROWS - 1) / ROWS;  // 2500
  fused_layer<true, true, true><<<nfused + ND, 256, 0, stream>>>(
      xh, off, eidx, WT1, h1h, N, E, nfused, sim, mri, maskf, simh, rs, ND);

  // ---- fused layer 2 (writes fp32 d_out) ----
  fused_layer<false, false, false><<<nfused, 256, 0, stream>>>(
      h1h, off, eidx, WT2, out, N, E, nfused, nullptr, nullptr, nullptr,
      nullptr, nullptr, 0);

  // ---- similarity diffusion ----
  gather2_k<<<(ND * 32 + 255) / 256, 256, 0, stream>>>(out, bli, mri, hbp, hbs, ND);
  dim3 tgrid(KP / 64, DD / 64);
  transpose_k<<<tgrid, 256, 0, stream>>>(hbs, hbsT);
  dim3 sgrid((ND + 63) / 64, KSPLIT);
  sim_mfma<<<sgrid, 256, 0, stream>>>(simh, hbsT, hs_part, ND);
  reduce_k<<<(ND * DD / 4 + 255) / 256, 256, 0, stream>>>(hs_part, hs, ND * DD / 4);
  final_k<<<(ND * 32 + 255) / 256, 256, 0, stream>>>(hs, hbp, rs, bli, deg, out, ND);
}

// Round 9
// 508.406 us; speedup vs baseline: 1.1858x; 1.1858x over previous
//
#include <hip/hip_runtime.h>
#include <hip/hip_bf16.h>

#define DD 128
#define RR 8
#define KK 1152      // RGCN composite K = 128 + 8*128
#define SCAN_CHUNK 2048
#define KSPLIT 8
#define KP 4096      // padded sim K

typedef _Float16 h8 __attribute__((ext_vector_type(8)));
typedef _Float16 h4 __attribute__((ext_vector_type(4)));
typedef float f4 __attribute__((ext_vector_type(4)));

__device__ __forceinline__ void gload16(const _Float16* g, _Float16* l) {
  __builtin_amdgcn_global_load_lds(
      (const __attribute__((address_space(1))) void*)g,
      (__attribute__((address_space(3))) void*)l, 16, 0, 0);
}

// ---------------- 3-phase exclusive scan of cnt -> off ----------------
__global__ __launch_bounds__(256) void scan_a(const int* __restrict__ cnt,
    int* __restrict__ off, int* __restrict__ bsum, int n) {
  __shared__ int red[256];
  int base = blockIdx.x * SCAN_CHUNK + threadIdx.x * 8;
  int v[8];
  int s = 0;
#pragma unroll
  for (int i = 0; i < 8; ++i) {
    int idx = base + i;
    v[i] = s;
    s += (idx < n) ? cnt[idx] : 0;
  }
  red[threadIdx.x] = s;
  __syncthreads();
  for (int o = 1; o < 256; o <<= 1) {
    int t = (threadIdx.x >= o) ? red[threadIdx.x - o] : 0;
    __syncthreads();
    red[threadIdx.x] += t;
    __syncthreads();
  }
  int pre = (threadIdx.x > 0) ? red[threadIdx.x - 1] : 0;
#pragma unroll
  for (int i = 0; i < 8; ++i) {
    int idx = base + i;
    if (idx < n) off[idx] = v[i] + pre;
  }
  if (threadIdx.x == 255) bsum[blockIdx.x] = red[255];
}

__global__ void scan_b(int* __restrict__ bsum, int nb) {
  if (threadIdx.x == 0) {
    int s = 0;
    for (int i = 0; i < nb; ++i) { int t = bsum[i]; bsum[i] = s; s += t; }
  }
}

__global__ __launch_bounds__(256) void scan_c(int* __restrict__ off,
    const int* __restrict__ bsum, int n) {
  int i = blockIdx.x * 256 + threadIdx.x;
  if (i < n) off[i] += bsum[i >> 11];
}

// ---------------- fill CSR ----------------
__global__ __launch_bounds__(256) void fill_k(const int* __restrict__ esrc,
    const int* __restrict__ edst, const int* __restrict__ etyp,
    int* __restrict__ cur, int* __restrict__ eidx, int E) {
  int e = blockIdx.x * 256 + threadIdx.x;
  if (e < E) {
    int seg = edst[e] * RR + etyp[e];
    int p = atomicAdd(&cur[seg], 1);
    eidx[p] = esrc[e];
  }
}

// ---------------- fused prep: convx | convw x2 | maskset | count ----------
__global__ __launch_bounds__(256) void prep_k(
    const float* __restrict__ x, _Float16* __restrict__ xh, int n4x,
    const float* __restrict__ W1s, const float* __restrict__ W1r,
    _Float16* __restrict__ WT1,
    const float* __restrict__ W2s, const float* __restrict__ W2r,
    _Float16* __restrict__ WT2,
    const int* __restrict__ mri, float* __restrict__ maskf, int nd,
    const int* __restrict__ edst, const int* __restrict__ etyp,
    int* __restrict__ cnt, int* __restrict__ deg, int E,
    int bX, int bW, int bM) {
  int b = blockIdx.x, t = threadIdx.x;
  if (b < bX) {
    int i = b * 256 + t;
    if (i < n4x) {
      float4 v = *(const float4*)(x + (size_t)i * 4);
      h4 o = {(_Float16)v.x, (_Float16)v.y, (_Float16)v.z, (_Float16)v.w};
      *(h4*)(xh + (size_t)i * 4) = o;
    }
  } else if (b < bX + 2 * bW) {
    int wi = (b - bX) / bW;                       // 0 or 1
    int g = (b - bX - wi * bW) * 256 + t;
    if (g < DD * KK) {
      int n = g / KK, k = g % KK;
      const float* Ws = wi ? W2s : W1s;
      const float* Wr = wi ? W2r : W1r;
      float v = (k < DD) ? Ws[(size_t)k * DD + n] : Wr[(size_t)(k - DD) * DD + n];
      (wi ? WT2 : WT1)[g] = (_Float16)v;
    }
  } else if (b < bX + 2 * bW + bM) {
    int i = (b - bX - 2 * bW) * 256 + t;
    if (i < nd) maskf[mri[i]] = 1.0f;
  } else {
    int i = (b - bX - 2 * bW - bM) * 256 + t;
    if (i < E) {
      int d = edst[i];
      atomicAdd(&cnt[d * RR + etyp[i]], 1);
      atomicAdd(&deg[d], 1);
    }
  }
}

// ---------------- sim row convert + fused rowsum (body) ----------------
__device__ __forceinline__ void convsim_body(const float* __restrict__ sim,
    const int* __restrict__ mri, const float* __restrict__ maskf,
    _Float16* __restrict__ simh, float* __restrict__ rs, int nd, int i,
    float* red) {
  const float* row = sim + (size_t)mri[i] * nd;
  float acc = 0.f;
  for (int c4 = threadIdx.x; c4 < KP / 4; c4 += 256) {
    int c = c4 * 4;
    float4 v = make_float4(0.f, 0.f, 0.f, 0.f);
    if (c < nd) {
      v = *(const float4*)(row + c);
      float4 mk = *(const float4*)(maskf + c);
      acc += v.x * mk.x + v.y * mk.y + v.z * mk.z + v.w * mk.w;
    }
    h4 o = {(_Float16)v.x, (_Float16)v.y, (_Float16)v.z, (_Float16)v.w};
    *(h4*)(simh + (size_t)i * KP + c) = o;
  }
  red[threadIdx.x] = acc;
  __syncthreads();
  for (int o = 128; o > 0; o >>= 1) {
    if (threadIdx.x < o) red[threadIdx.x] += red[threadIdx.x + o];
    __syncthreads();
  }
  if (threadIdx.x == 0) rs[i] = red[0] + 1e-9f;
}

// ---------------- chunked layer step: gemm(chunk i) || agg(chunk i+1) -----
// Roles by blockIdx: [0,nGemm) = 64x128 MFMA GEMM on rows [gemmBase, ...);
// [nGemm, nGemm+nAgg) = CSR mean-aggregation for row aggBase+j (8 segs);
// rest (COSIM only) = convsim rows. GEMM: A gload-dbuf (16KB), B single-buf
// reg-staged issue-early/write-late (16KB) -> 32KB LDS, 5 blocks/CU.
template <bool RELU, bool F16OUT, bool COSIM>
__global__ __launch_bounds__(256) void layer_step(
    const _Float16* __restrict__ hsrc, const int* __restrict__ off,
    const int* __restrict__ eidx, const _Float16* __restrict__ WT,
    void* __restrict__ outv, _Float16* __restrict__ msg,
    int nN, int E, int gemmBase, int nGemm, int aggBase, int nAgg,
    const float* __restrict__ sim, const int* __restrict__ mri,
    const float* __restrict__ maskf, _Float16* __restrict__ simh,
    float* __restrict__ rs, int nd) {
  __shared__ char smem[32768];
  const int b = blockIdx.x;
  const int t = threadIdx.x;

  if (b >= nGemm + nAgg) {
    if (COSIM)
      convsim_body(sim, mri, maskf, simh, rs, nd, b - nGemm - nAgg,
                   (float*)smem);
    return;
  }

  if (b >= nGemm) {
    // ---------- aggregation role: one dst row, 8 (row,rel) segments ------
    const int row = aggBase + (b - nGemm);
    const int q = t & 31;
    const int seg = row * RR + (t >> 5);
    int bo = off[seg];
    int e = (seg + 1 < nN * RR) ? off[seg + 1] : E;
    int n = e - bo;
    float a0 = 0.f, a1 = 0.f, a2 = 0.f, a3 = 0.f;
    if (n > 0) {
      int e1 = e - 1;
      int s0 = eidx[bo];
      int s1 = eidx[min(bo + 1, e1)];
      int s2 = eidx[min(bo + 2, e1)];
      int s3 = eidx[min(bo + 3, e1)];
      h4 v0 = *(const h4*)(hsrc + (size_t)s0 * DD + q * 4);
      h4 v1 = *(const h4*)(hsrc + (size_t)s1 * DD + q * 4);
      h4 v2 = *(const h4*)(hsrc + (size_t)s2 * DD + q * 4);
      h4 v3 = *(const h4*)(hsrc + (size_t)s3 * DD + q * 4);
      a0 = (float)v0[0]; a1 = (float)v0[1]; a2 = (float)v0[2]; a3 = (float)v0[3];
      if (n > 1) { a0 += (float)v1[0]; a1 += (float)v1[1]; a2 += (float)v1[2]; a3 += (float)v1[3]; }
      if (n > 2) { a0 += (float)v2[0]; a1 += (float)v2[1]; a2 += (float)v2[2]; a3 += (float)v2[3]; }
      if (n > 3) { a0 += (float)v3[0]; a1 += (float)v3[1]; a2 += (float)v3[2]; a3 += (float)v3[3]; }
      for (int i = bo + 4; i < e; ++i) {
        int s = eidx[i];
        h4 v = *(const h4*)(hsrc + (size_t)s * DD + q * 4);
        a0 += (float)v[0]; a1 += (float)v[1]; a2 += (float)v[2]; a3 += (float)v[3];
      }
    }
    float ic = (n > 0) ? 1.0f / (float)n : 0.0f;
    h4 o = {(_Float16)(a0 * ic), (_Float16)(a1 * ic),
            (_Float16)(a2 * ic), (_Float16)(a3 * ic)};
    *(h4*)(msg + (size_t)seg * DD + q * 4) = o;   // plain store: keep in L3
    return;
  }

  // ---------- GEMM role: out[row0..row0+64) = [hsrc | msg] @ WT^T --------
  _Float16* Ab = (_Float16*)smem;              // [2][64*64]
  _Float16* Bs = (_Float16*)(smem + 16384);    // [128][64] swizzled
  const int lane = t & 63, w = t >> 6;
  const int row0 = gemmBase + b * 64;
  const int wm = w >> 1, wn = w & 1;
  const int lr = lane & 15, lg = lane >> 4;

  f4 acc[2][4];
#pragma unroll
  for (int mi = 0; mi < 2; ++mi)
#pragma unroll
    for (int ni = 0; ni < 4; ++ni) acc[mi][ni] = (f4){0.f, 0.f, 0.f, 0.f};

  // A staging (gload, dbuf): 512 16B chunks
  const _Float16* pxh[2];
  const _Float16* pmsg[2];
  int ldsA[2];
#pragma unroll
  for (int j = 0; j < 2; ++j) {
    int q = j * 256 + w * 64 + lane;
    int row = q >> 3;
    int gck = (q & 7) ^ (row & 7);
    int m = row0 + row; if (m >= nN) m = nN - 1;
    pxh[j]  = hsrc + (size_t)m * DD + gck * 8;
    pmsg[j] = msg + (size_t)m * (RR * DD) + gck * 8;
    ldsA[j] = (j * 256 + w * 64) * 8;
  }
  // B reg-staging: thread owns WT row bn, chunks bc0..bc0+3
  const int bn = t >> 1, bc0 = (t & 1) * 4;
  const _Float16* wrow = WT + (size_t)bn * KK;
  uint4 breg[4];

  const int nsteps = KK / 64;  // 18
  // prologue: A(0) -> Ab[0], B(0) -> regs -> Bs
#pragma unroll
  for (int j = 0; j < 2; ++j) gload16(pxh[j], &Ab[ldsA[j]]);
#pragma unroll
  for (int j = 0; j < 4; ++j)
    breg[j] = *(const uint4*)(wrow + (size_t)(bc0 + j) * 8);
#pragma unroll
  for (int j = 0; j < 4; ++j) {
    int c = bc0 + j, csw = c ^ (bn & 7);
    *(uint4*)&Bs[bn * 64 + csw * 8] = breg[j];
  }
  asm volatile("s_waitcnt vmcnt(0)" ::: "memory");
  __syncthreads();

  for (int ts = 0; ts < nsteps; ++ts) {
    const int cur = ts & 1;
    if (ts + 1 < nsteps) {
      const int kk = (ts + 1) * 64;
      const int nxt = cur ^ 1;
#pragma unroll
      for (int j = 0; j < 4; ++j)           // B(ts+1) -> regs (early)
        breg[j] = *(const uint4*)(wrow + kk + (size_t)(bc0 + j) * 8);
      if (kk < DD) {
#pragma unroll
        for (int j = 0; j < 2; ++j) gload16(pxh[j] + kk, &Ab[nxt * 4096 + ldsA[j]]);
      } else {
#pragma unroll
        for (int j = 0; j < 2; ++j) gload16(pmsg[j] + (kk - DD), &Ab[nxt * 4096 + ldsA[j]]);
      }
    }
#pragma unroll
    for (int s = 0; s < 2; ++s) {
      h8 af[2], bf[4];
#pragma unroll
      for (int mi = 0; mi < 2; ++mi) {
        int r = wm * 32 + mi * 16 + lr;
        af[mi] = *(const h8*)&Ab[cur * 4096 + r * 64 + (((s * 4 + lg) ^ (r & 7)) << 3)];
      }
#pragma unroll
      for (int ni = 0; ni < 4; ++ni) {
        int n = wn * 64 + ni * 16 + lr;
        bf[ni] = *(const h8*)&Bs[n * 64 + (((s * 4 + lg) ^ (n & 7)) << 3)];
      }
#pragma unroll
      for (int mi = 0; mi < 2; ++mi)
#pragma unroll
        for (int ni = 0; ni < 4; ++ni)
          acc[mi][ni] = __builtin_amdgcn_mfma_f32_16x16x32_f16(
              af[mi], bf[ni], acc[mi][ni], 0, 0, 0);
    }
    __syncthreads();                        // all waves done reading Bs(ts)
    if (ts + 1 < nsteps) {
#pragma unroll
      for (int j = 0; j < 4; ++j) {         // write B(ts+1) late
        int c = bc0 + j, csw = c ^ (bn & 7);
        *(uint4*)&Bs[bn * 64 + csw * 8] = breg[j];
      }
    }
    asm volatile("s_waitcnt vmcnt(0)" ::: "memory");  // A(ts+1) landed
    __syncthreads();
  }

  // epilogue: C/D layout col=lane&15, row=(lane>>4)*4+reg
#pragma unroll
  for (int mi = 0; mi < 2; ++mi) {
#pragma unroll
    for (int j = 0; j < 4; ++j) {
      int row = row0 + wm * 32 + mi * 16 + lg * 4 + j;
      if (row < nN) {
#pragma unroll
        for (int ni = 0; ni < 4; ++ni) {
          int col = wn * 64 + ni * 16 + lr;
          float v = acc[mi][ni][j];
          if (RELU) v = fmaxf(v, 0.f);
          if (F16OUT)
            ((_Float16*)outv)[(size_t)row * DD + col] = (_Float16)v;
          else
            ((float*)outv)[(size_t)row * DD + col] = v;
        }
      }
    }
  }
}

// ---------------- gather disease rows (fp32 hbp) + scatter f16 into hbs ----
__global__ __launch_bounds__(256) void gather2_k(const float* __restrict__ h2,
    const int* __restrict__ bli, const int* __restrict__ mri,
    float* __restrict__ hbp, _Float16* __restrict__ hbs, int nd) {
  int gid = blockIdx.x * 256 + threadIdx.x;
  int i = gid >> 5, q = gid & 31;
  if (i < nd) {
    float4 v = *(const float4*)(h2 + (size_t)bli[i] * DD + q * 4);
    *(float4*)(hbp + (size_t)i * DD + q * 4) = v;
    h4 o = {(_Float16)v.x, (_Float16)v.y, (_Float16)v.z, (_Float16)v.w};
    *(h4*)(hbs + (size_t)mri[i] * DD + q * 4) = o;
  }
}

// ---------------- transpose hbs[KP][128] -> hbsT[128][KP] ----------------
__global__ __launch_bounds__(256) void transpose_k(const _Float16* __restrict__ hbs,
    _Float16* __restrict__ hbsT) {
  __shared__ _Float16 tile[64][72];
  int r0 = blockIdx.x * 64, c0 = blockIdx.y * 64;
  int t = threadIdx.x;
  int r = t >> 2, cs = (t & 3) * 16;
  *(h8*)&tile[r][cs]     = *(const h8*)(hbs + (size_t)(r0 + r) * DD + c0 + cs);
  *(h8*)&tile[r][cs + 8] = *(const h8*)(hbs + (size_t)(r0 + r) * DD + c0 + cs + 8);
  __syncthreads();
  int n = t >> 2, rs2 = (t & 3) * 16;
  h8 o0, o1;
#pragma unroll
  for (int j = 0; j < 8; ++j) {
    o0[j] = tile[rs2 + j][n];
    o1[j] = tile[rs2 + 8 + j][n];
  }
  *(h8*)(hbsT + (size_t)(c0 + n) * KP + r0 + rs2)     = o0;
  *(h8*)(hbsT + (size_t)(c0 + n) * KP + r0 + rs2 + 8) = o1;
}

// ---------------- sim MFMA GEMM: hs_part[ky] = simh[:, kchunk] @ hbsT^T ----
__global__ __launch_bounds__(256) void sim_mfma(const _Float16* __restrict__ simh,
    const _Float16* __restrict__ hbsT, float* __restrict__ hs_part, int nd) {
  __shared__ _Float16 Ab[2][64 * 64];
  __shared__ _Float16 Bb[2][128 * 64];
  const int t = threadIdx.x;
  const int lane = t & 63, w = t >> 6;
  const int row0 = blockIdx.x * 64;
  const int kb0 = blockIdx.y * (KP / KSPLIT);
  const int wm = w >> 1, wn = w & 1;
  const int lr = lane & 15, lg = lane >> 4;

  f4 acc[2][4];
#pragma unroll
  for (int mi = 0; mi < 2; ++mi)
#pragma unroll
    for (int ni = 0; ni < 4; ++ni) acc[mi][ni] = (f4){0.f, 0.f, 0.f, 0.f};

  const _Float16* pA[2];
  int ldsA[2];
#pragma unroll
  for (int j = 0; j < 2; ++j) {
    int q = j * 256 + w * 64 + lane;
    int row = q >> 3;
    int gck = (q & 7) ^ (row & 7);
    int m = row0 + row; if (m >= nd) m = nd - 1;
    pA[j] = simh + (size_t)m * KP + kb0 + gck * 8;
    ldsA[j] = (j * 256 + w * 64) * 8;
  }
  const _Float16* pB[4];
  int ldsB[4];
#pragma unroll
  for (int i = 0; i < 4; ++i) {
    int q = i * 256 + w * 64 + lane;
    int n = q >> 3;
    int gck = (q & 7) ^ (n & 7);
    pB[i] = hbsT + (size_t)n * KP + kb0 + gck * 8;
    ldsB[i] = (i * 256 + w * 64) * 8;
  }

  const int nsteps = (KP / KSPLIT) / 64;  // 8
#pragma unroll
  for (int j = 0; j < 2; ++j) gload16(pA[j], &Ab[0][ldsA[j]]);
#pragma unroll
  for (int i = 0; i < 4; ++i) gload16(pB[i], &Bb[0][ldsB[i]]);
  asm volatile("s_waitcnt vmcnt(0)" ::: "memory");
  __syncthreads();

  for (int ts = 0; ts < nsteps; ++ts) {
    const int cur = ts & 1;
    if (ts + 1 < nsteps) {
      const int kk = (ts + 1) * 64;
      const int nxt = cur ^ 1;
#pragma unroll
      for (int j = 0; j < 2; ++j) gload16(pA[j] + kk, &Ab[nxt][ldsA[j]]);
#pragma unroll
      for (int i = 0; i < 4; ++i) gload16(pB[i] + kk, &Bb[nxt][ldsB[i]]);
    }
#pragma unroll
    for (int s = 0; s < 2; ++s) {
      h8 af[2], bf[4];
#pragma unroll
      for (int mi = 0; mi < 2; ++mi) {
        int r = wm * 32 + mi * 16 + lr;
        af[mi] = *(const h8*)&Ab[cur][r * 64 + (((s * 4 + lg) ^ (r & 7)) << 3)];
      }
#pragma unroll
      for (int ni = 0; ni < 4; ++ni) {
        int n = wn * 64 + ni * 16 + lr;
        bf[ni] = *(const h8*)&Bb[cur][n * 64 + (((s * 4 + lg) ^ (n & 7)) << 3)];
      }
#pragma unroll
      for (int mi = 0; mi < 2; ++mi)
#pragma unroll
        for (int ni = 0; ni < 4; ++ni)
          acc[mi][ni] = __builtin_amdgcn_mfma_f32_16x16x32_f16(
              af[mi], bf[ni], acc[mi][ni], 0, 0, 0);
    }
    asm volatile("s_waitcnt vmcnt(0)" ::: "memory");
    __syncthreads();
  }

  float* dst = hs_part + (size_t)blockIdx.y * nd * DD;
#pragma unroll
  for (int mi = 0; mi < 2; ++mi) {
#pragma unroll
    for (int j = 0; j < 4; ++j) {
      int row = row0 + wm * 32 + mi * 16 + lg * 4 + j;
      if (row < nd) {
#pragma unroll
        for (int ni = 0; ni < 4; ++ni) {
          int col = wn * 64 + ni * 16 + lr;
          dst[(size_t)row * DD + col] = acc[mi][ni][j];
        }
      }
    }
  }
}

// ---------------- fused K-split reduce + final blend ----------------------
__global__ __launch_bounds__(256) void reduce_final_k(
    const float* __restrict__ part, const float* __restrict__ hbp,
    const float* __restrict__ rs, const int* __restrict__ bli,
    const int* __restrict__ deg, float* __restrict__ out, int nd) {
  int gid = blockIdx.x * 256 + threadIdx.x;
  int i = gid >> 5, q = gid & 31;
  if (i < nd) {
    f4 s = (f4){0.f, 0.f, 0.f, 0.f};
#pragma unroll
    for (int p = 0; p < KSPLIT; ++p)
      s += *(const f4*)(part + (size_t)p * nd * DD + (size_t)i * DD + q * 4);
    int g = bli[i];
    float cg = 0.7f * expf(-0.7f * (float)deg[g]) + 0.2f;
    float inv = 1.0f / rs[i];
    f4 bb = *(const f4*)(hbp + (size_t)i * DD + q * 4);
    f4 o;
#pragma unroll
    for (int j = 0; j < 4; ++j) o[j] = cg * (s[j] * inv) + (1.f - cg) * bb[j];
    *(f4*)(out + (size_t)g * DD + q * 4) = o;
  }
}

extern "C" void kernel_launch(void* const* d_in, const int* in_sizes, int n_in,
                              void* d_out, int out_size, void* d_ws, size_t ws_size,
                              hipStream_t stream) {
  const float* x   = (const float*)d_in[0];
  const float* sim = (const float*)d_in[1];
  const float* W1s = (const float*)d_in[2];
  const float* W1r = (const float*)d_in[3];
  const float* W2s = (const float*)d_in[4];
  const float* W2r = (const float*)d_in[5];
  const int* esrc  = (const int*)d_in[6];
  const int* edst  = (const int*)d_in[7];
  const int* etyp  = (const int*)d_in[8];
  const int* bli   = (const int*)d_in[9];
  const int* mri   = (const int*)d_in[10];
  const int N  = in_sizes[0] / DD;
  const int E  = in_sizes[6];
  const int ND = in_sizes[9];
  const int NR = N * RR;
  float* out = (float*)d_out;

  // workspace carve-up (~163 MB)
  char* w = (char*)d_ws;
  _Float16* msg  = (_Float16*)w; w += (size_t)NR * DD * sizeof(_Float16);   // 82 MB
  _Float16* xh   = (_Float16*)w; w += (size_t)N * DD * sizeof(_Float16);
  _Float16* h1h  = (_Float16*)w; w += (size_t)N * DD * sizeof(_Float16);
  _Float16* WT1  = (_Float16*)w; w += (size_t)DD * KK * sizeof(_Float16);
  _Float16* WT2  = (_Float16*)w; w += (size_t)DD * KK * sizeof(_Float16);
  _Float16* simh = (_Float16*)w; w += (size_t)ND * KP * sizeof(_Float16);
  _Float16* hbs  = (_Float16*)w; w += (size_t)KP * DD * sizeof(_Float16);
  _Float16* hbsT = (_Float16*)w; w += (size_t)DD * KP * sizeof(_Float16);
  float* hs_part = (float*)w; w += (size_t)KSPLIT * ND * DD * sizeof(float);
  float* hbp   = (float*)w; w += (size_t)ND * DD * sizeof(float);
  float* maskf = (float*)w; w += (size_t)KP * sizeof(float);
  int* cnt  = (int*)w; w += (size_t)NR * sizeof(int);
  int* deg  = (int*)w; w += (size_t)N * sizeof(int);
  int* off  = (int*)w; w += (size_t)NR * sizeof(int);
  int* cur  = (int*)w; w += (size_t)NR * sizeof(int);
  int* eidx = (int*)w; w += (size_t)E * sizeof(int);
  int* bsum = (int*)w; w += 1024 * sizeof(int);
  float* rs = (float*)w; w += (size_t)ND * sizeof(float);

  // ---- zero + fused prep (convx | convw | maskset | count) ----
  hipMemsetAsync(cnt, 0, (size_t)(NR + N) * sizeof(int), stream);
  hipMemsetAsync(maskf, 0, (size_t)KP * sizeof(float), stream);
  hipMemsetAsync(hbs, 0, (size_t)KP * DD * sizeof(_Float16), stream);
  const int n4x = N * DD / 4;
  const int bX = (n4x + 255) / 256;
  const int bW = (DD * KK + 255) / 256;
  const int bM = (ND + 255) / 256;
  const int bC = (E + 255) / 256;
  prep_k<<<bX + 2 * bW + bM + bC, 256, 0, stream>>>(
      x, xh, n4x, W1s, W1r, WT1, W2s, W2r, WT2, mri, maskf, ND,
      edst, etyp, cnt, deg, E, bX, bW, bM);

  // ---- CSR scan + fill ----
  int nblk = (NR + SCAN_CHUNK - 1) / SCAN_CHUNK;
  scan_a<<<nblk, 256, 0, stream>>>(cnt, off, bsum, NR);
  scan_b<<<1, 256, 0, stream>>>(bsum, nblk);
  scan_c<<<(NR + 255) / 256, 256, 0, stream>>>(off, bsum, NR);
  hipMemcpyAsync(cur, off, (size_t)NR * sizeof(int), hipMemcpyDeviceToDevice, stream);
  fill_k<<<(E + 255) / 256, 256, 0, stream>>>(esrc, edst, etyp, cur, eidx, E);

  // ---- chunk boundaries (64-aligned) ----
  int cb[5];
  for (int i = 0; i <= 4; ++i) {
    long v = ((long)N * i / 4 + 63) / 64 * 64;
    cb[i] = (int)((v > N) ? N : v);
  }
  cb[4] = N;

  // ---- layer 1: agg(c0)+convsim, then gemm(ci) || agg(c{i+1}) ----
  layer_step<true, true, true><<<(cb[1] - cb[0]) + ND, 256, 0, stream>>>(
      xh, off, eidx, WT1, h1h, msg, N, E, 0, 0, cb[0], cb[1] - cb[0],
      sim, mri, maskf, simh, rs, ND);
  for (int i = 0; i < 4; ++i) {
    int ng = (cb[i + 1] - cb[i]) / 64;
    int na = (i < 3) ? (cb[i + 2] - cb[i + 1]) : 0;
    layer_step<true, true, false><<<ng + na, 256, 0, stream>>>(
        xh, off, eidx, WT1, h1h, msg, N, E, cb[i], ng, cb[i + 1], na,
        nullptr, nullptr, nullptr, nullptr, nullptr, 0);
  }

  // ---- layer 2 (writes fp32 d_out) ----
  layer_step<false, false, false><<<cb[1] - cb[0], 256, 0, stream>>>(
      h1h, off, eidx, WT2, out, msg, N, E, 0, 0, cb[0], cb[1] - cb[0],
      nullptr, nullptr, nullptr, nullptr, nullptr, 0);
  for (int i = 0; i < 4; ++i) {
    int ng = (cb[i + 1] - cb[i]) / 64;
    int na = (i < 3) ? (cb[i + 2] - cb[i + 1]) : 0;
    layer_step<false, false, false><<<ng + na, 256, 0, stream>>>(
        h1h, off, eidx, WT2, out, msg, N, E, cb[i], ng, cb[i + 1], na,
        nullptr, nullptr, nullptr, nullptr, nullptr, 0);
  }

  // ---- similarity diffusion ----
  gather2_k<<<(ND * 32 + 255) / 256, 256, 0, stream>>>(out, bli, mri, hbp, hbs, ND);
  dim3 tgrid(KP / 64, DD / 64);
  transpose_k<<<tgrid, 256, 0, stream>>>(hbs, hbsT);
  dim3 sgrid((ND + 63) / 64, KSPLIT);
  sim_mfma<<<sgrid, 256, 0, stream>>>(simh, hbsT, hs_part, ND);
  reduce_final_k<<<(ND * 32 + 255) / 256, 256, 0, stream>>>(
      hs_part, hbp, rs, bli, deg, out, ND);
}

// Round 10
// 266.387 us; speedup vs baseline: 2.2632x; 1.9085x over previous
//
#include <hip/hip_runtime.h>
#include <hip/hip_bf16.h>

#define DD 128
#define RR 8
#define KK 1152      // RGCN composite K = 128 + 8*128
#define SCAN_CHUNK 2048
#define KSPLIT 8
#define KP 4096      // padded sim K

typedef _Float16 h8 __attribute__((ext_vector_type(8)));
typedef _Float16 h4 __attribute__((ext_vector_type(4)));
typedef float f4 __attribute__((ext_vector_type(4)));

__device__ __forceinline__ void gload16(const _Float16* g, _Float16* l) {
  __builtin_amdgcn_global_load_lds(
      (const __attribute__((address_space(1))) void*)g,
      (__attribute__((address_space(3))) void*)l, 16, 0, 0);
}

// ---------------- count edges per (dst, rel) (deg derived from off later) --
__global__ __launch_bounds__(256) void count_k(const int* __restrict__ edst,
    const int* __restrict__ etyp, int* __restrict__ cnt, int E) {
  int i = blockIdx.x * 256 + threadIdx.x;
  if (i < E) atomicAdd(&cnt[edst[i] * RR + etyp[i]], 1);
}

// ---------------- 3-phase exclusive scan of cnt -> off ----------------
__global__ __launch_bounds__(256) void scan_a(const int* __restrict__ cnt,
    int* __restrict__ off, int* __restrict__ bsum, int n) {
  __shared__ int red[256];
  int base = blockIdx.x * SCAN_CHUNK + threadIdx.x * 8;
  int v[8];
  int s = 0;
#pragma unroll
  for (int i = 0; i < 8; ++i) {
    int idx = base + i;
    v[i] = s;
    s += (idx < n) ? cnt[idx] : 0;
  }
  red[threadIdx.x] = s;
  __syncthreads();
  for (int o = 1; o < 256; o <<= 1) {
    int t = (threadIdx.x >= o) ? red[threadIdx.x - o] : 0;
    __syncthreads();
    red[threadIdx.x] += t;
    __syncthreads();
  }
  int pre = (threadIdx.x > 0) ? red[threadIdx.x - 1] : 0;
#pragma unroll
  for (int i = 0; i < 8; ++i) {
    int idx = base + i;
    if (idx < n) off[idx] = v[i] + pre;
  }
  if (threadIdx.x == 255) bsum[blockIdx.x] = red[255];
}

__global__ void scan_b(int* __restrict__ bsum, int nb) {
  if (threadIdx.x == 0) {
    int s = 0;
    for (int i = 0; i < nb; ++i) { int t = bsum[i]; bsum[i] = s; s += t; }
  }
}

__global__ __launch_bounds__(256) void scan_c(int* __restrict__ off,
    const int* __restrict__ bsum, int n) {
  int i = blockIdx.x * 256 + threadIdx.x;
  if (i < n) off[i] += bsum[i >> 11];
}

// ---------------- fill CSR ----------------
__global__ __launch_bounds__(256) void fill_k(const int* __restrict__ esrc,
    const int* __restrict__ edst, const int* __restrict__ etyp,
    int* __restrict__ cur, int* __restrict__ eidx, int E) {
  int e = blockIdx.x * 256 + threadIdx.x;
  if (e < E) {
    int seg = edst[e] * RR + etyp[e];
    int p = atomicAdd(&cur[seg], 1);
    eidx[p] = esrc[e];
  }
}

// ---------------- fp32 -> f16 convert of x ----------------
__global__ __launch_bounds__(256) void convx_k(const float* __restrict__ x,
    _Float16* __restrict__ xh, int n4) {
  int i = blockIdx.x * 256 + threadIdx.x;
  if (i < n4) {
    float4 v = *(const float4*)(x + (size_t)i * 4);
    h4 o = {(_Float16)v.x, (_Float16)v.y, (_Float16)v.z, (_Float16)v.w};
    *(h4*)(xh + (size_t)i * 4) = o;
  }
}

// ---------------- transposed f16 weights via LDS tile (both sides coalesced)
// W[k][n] (Ws k<128, Wr k>=128) -> WT[n][k]. Tiles 64(k) x 64(n).
__global__ __launch_bounds__(256) void convwT_k(const float* __restrict__ Ws,
    const float* __restrict__ Wr, _Float16* __restrict__ WT) {
  __shared__ _Float16 tile[64][72];
  const int k0 = blockIdx.x * 64, n0 = blockIdx.y * 64;
  const int t = threadIdx.x;
  {
    int kr = t >> 2, c0 = (t & 3) * 16;
    int k = k0 + kr;
    const float* src = (k < DD) ? (Ws + (size_t)k * DD + n0 + c0)
                                : (Wr + (size_t)(k - DD) * DD + n0 + c0);
#pragma unroll
    for (int j = 0; j < 16; j += 4) {
      float4 v = *(const float4*)(src + j);
      tile[kr][c0 + j + 0] = (_Float16)v.x;
      tile[kr][c0 + j + 1] = (_Float16)v.y;
      tile[kr][c0 + j + 2] = (_Float16)v.z;
      tile[kr][c0 + j + 3] = (_Float16)v.w;
    }
  }
  __syncthreads();
  {
    int nr = t >> 2, ck = (t & 3) * 16;
    h8 o0, o1;
#pragma unroll
    for (int j = 0; j < 8; ++j) {
      o0[j] = tile[ck + j][nr];
      o1[j] = tile[ck + 8 + j][nr];
    }
    *(h8*)(WT + (size_t)(n0 + nr) * KK + k0 + ck) = o0;
    *(h8*)(WT + (size_t)(n0 + nr) * KK + k0 + ck + 8) = o1;
  }
}

// ---------------- aggregation body: 16 lanes/seg, h8 loads, 4-deep pipeline
__device__ __forceinline__ void agg_body(const _Float16* __restrict__ h,
    const int* __restrict__ off, const int* __restrict__ eidx,
    _Float16* __restrict__ msg, int nseg, int E, int gid) {
  int seg = gid >> 4, q = gid & 15;
  if (seg >= nseg) return;
  int b = off[seg];
  int e = (seg + 1 < nseg) ? off[seg + 1] : E;
  int n = e - b;
  float a[8];
#pragma unroll
  for (int j = 0; j < 8; ++j) a[j] = 0.f;
  if (n > 0) {
    int e1 = e - 1;
    // 4 independent index loads, then 4 independent 16B gathers
    int s0 = eidx[b];
    int s1 = eidx[min(b + 1, e1)];
    int s2 = eidx[min(b + 2, e1)];
    int s3 = eidx[min(b + 3, e1)];
    h8 v0 = *(const h8*)(h + (size_t)s0 * DD + q * 8);
    h8 v1 = *(const h8*)(h + (size_t)s1 * DD + q * 8);
    h8 v2 = *(const h8*)(h + (size_t)s2 * DD + q * 8);
    h8 v3 = *(const h8*)(h + (size_t)s3 * DD + q * 8);
#pragma unroll
    for (int j = 0; j < 8; ++j) a[j] = (float)v0[j];
    if (n > 1) {
#pragma unroll
      for (int j = 0; j < 8; ++j) a[j] += (float)v1[j];
    }
    if (n > 2) {
#pragma unroll
      for (int j = 0; j < 8; ++j) a[j] += (float)v2[j];
    }
    if (n > 3) {
#pragma unroll
      for (int j = 0; j < 8; ++j) a[j] += (float)v3[j];
    }
    for (int i = b + 4; i < e; ++i) {  // rare tail
      int s = eidx[i];
      h8 v = *(const h8*)(h + (size_t)s * DD + q * 8);
#pragma unroll
      for (int j = 0; j < 8; ++j) a[j] += (float)v[j];
    }
  }
  float ic = (n > 0) ? 1.0f / (float)n : 0.0f;
  h8 o;
#pragma unroll
  for (int j = 0; j < 8; ++j) o[j] = (_Float16)(a[j] * ic);
  *(h8*)(msg + (size_t)seg * DD + q * 8) = o;
}

__global__ __launch_bounds__(256) void agg_k(const _Float16* __restrict__ h,
    const int* __restrict__ off, const int* __restrict__ eidx,
    _Float16* __restrict__ msg, int nseg, int E) {
  agg_body(h, off, eidx, msg, nseg, E, blockIdx.x * 256 + threadIdx.x);
}

// ---------------- sim row convert + fused rowsum (body) ----------------
__device__ __forceinline__ void convsim_body(const float* __restrict__ sim,
    const int* __restrict__ mri, const float* __restrict__ maskf,
    _Float16* __restrict__ simh, float* __restrict__ rs, int nd, int i,
    float* red) {
  const float* row = sim + (size_t)mri[i] * nd;
  float acc = 0.f;
  for (int c4 = threadIdx.x; c4 < KP / 4; c4 += 256) {
    int c = c4 * 4;
    float4 v = make_float4(0.f, 0.f, 0.f, 0.f);
    if (c < nd) {
      v = *(const float4*)(row + c);
      float4 mk = *(const float4*)(maskf + c);
      acc += v.x * mk.x + v.y * mk.y + v.z * mk.z + v.w * mk.w;
    }
    h4 o = {(_Float16)v.x, (_Float16)v.y, (_Float16)v.z, (_Float16)v.w};
    *(h4*)(simh + (size_t)i * KP + c) = o;
  }
  red[threadIdx.x] = acc;
  __syncthreads();
  for (int o = 128; o > 0; o >>= 1) {
    if (threadIdx.x < o) red[threadIdx.x] += red[threadIdx.x + o];
    __syncthreads();
  }
  if (threadIdx.x == 0) rs[i] = red[0] + 1e-9f;
}

// ---------------- co-scheduled: convsim (blocks 0..nd) + layer-1 agg ------
__global__ __launch_bounds__(256) void agg1_convsim_k(
    const _Float16* __restrict__ h, const int* __restrict__ off,
    const int* __restrict__ eidx, _Float16* __restrict__ msg, int nseg, int E,
    const float* __restrict__ sim, const int* __restrict__ mri,
    const float* __restrict__ maskf, _Float16* __restrict__ simh,
    float* __restrict__ rs, int nd) {
  __shared__ float red[256];
  if ((int)blockIdx.x < nd) {
    convsim_body(sim, mri, maskf, simh, rs, nd, blockIdx.x, red);
  } else {
    agg_body(h, off, eidx, msg, nseg, E,
             (blockIdx.x - nd) * 256 + threadIdx.x);
  }
}

// ---------------- MFMA RGCN GEMM: out = [xh | msg] @ WT^T ----------------
// 64x128 tile, BK=64, 4 waves of 32x64, double-buffered LDS, global_load_lds
// staging (linear LDS dest, inverse-XOR-swizzled global source, XOR on read).
template <bool RELU, bool F16OUT>
__global__ __launch_bounds__(256) void rgcn_mfma(const _Float16* __restrict__ xh,
    const _Float16* __restrict__ msg, const _Float16* __restrict__ WT,
    void* __restrict__ outv, int nN) {
  __shared__ _Float16 Ab[2][64 * 64];
  __shared__ _Float16 Bb[2][128 * 64];
  const int t = threadIdx.x;
  const int lane = t & 63, w = t >> 6;
  const int row0 = blockIdx.x * 64;
  const int wm = w >> 1, wn = w & 1;
  const int lr = lane & 15, lg = lane >> 4;

  f4 acc[2][4];
#pragma unroll
  for (int mi = 0; mi < 2; ++mi)
#pragma unroll
    for (int ni = 0; ni < 4; ++ni) acc[mi][ni] = (f4){0.f, 0.f, 0.f, 0.f};

  const _Float16* pxh[2];
  const _Float16* pmsg[2];
  int ldsA[2];
#pragma unroll
  for (int j = 0; j < 2; ++j) {
    int q = j * 256 + w * 64 + lane;
    int row = q >> 3;
    int gck = (q & 7) ^ (row & 7);
    int m = row0 + row; if (m >= nN) m = nN - 1;
    pxh[j] = xh + (size_t)m * DD + gck * 8;
    pmsg[j] = msg + (size_t)m * (RR * DD) + gck * 8;
    ldsA[j] = (j * 256 + w * 64) * 8;
  }
  const _Float16* pB[4];
  int ldsB[4];
#pragma unroll
  for (int i = 0; i < 4; ++i) {
    int q = i * 256 + w * 64 + lane;
    int n = q >> 3;
    int gck = (q & 7) ^ (n & 7);
    pB[i] = WT + (size_t)n * KK + gck * 8;
    ldsB[i] = (i * 256 + w * 64) * 8;
  }

  const int nsteps = KK / 64;  // 18
#pragma unroll
  for (int j = 0; j < 2; ++j) gload16(pxh[j], &Ab[0][ldsA[j]]);
#pragma unroll
  for (int i = 0; i < 4; ++i) gload16(pB[i], &Bb[0][ldsB[i]]);
  asm volatile("s_waitcnt vmcnt(0)" ::: "memory");
  __syncthreads();

  for (int ts = 0; ts < nsteps; ++ts) {
    const int cur = ts & 1;
    if (ts + 1 < nsteps) {
      const int kk = (ts + 1) * 64;
      const int nxt = cur ^ 1;
      if (kk < DD) {
#pragma unroll
        for (int j = 0; j < 2; ++j) gload16(pxh[j] + kk, &Ab[nxt][ldsA[j]]);
      } else {
#pragma unroll
        for (int j = 0; j < 2; ++j) gload16(pmsg[j] + (kk - DD), &Ab[nxt][ldsA[j]]);
      }
#pragma unroll
      for (int i = 0; i < 4; ++i) gload16(pB[i] + kk, &Bb[nxt][ldsB[i]]);
    }
#pragma unroll
    for (int s = 0; s < 2; ++s) {
      h8 af[2], bf[4];
#pragma unroll
      for (int mi = 0; mi < 2; ++mi) {
        int r = wm * 32 + mi * 16 + lr;
        af[mi] = *(const h8*)&Ab[cur][r * 64 + (((s * 4 + lg) ^ (r & 7)) << 3)];
      }
#pragma unroll
      for (int ni = 0; ni < 4; ++ni) {
        int n = wn * 64 + ni * 16 + lr;
        bf[ni] = *(const h8*)&Bb[cur][n * 64 + (((s * 4 + lg) ^ (n & 7)) << 3)];
      }
#pragma unroll
      for (int mi = 0; mi < 2; ++mi)
#pragma unroll
        for (int ni = 0; ni < 4; ++ni)
          acc[mi][ni] = __builtin_amdgcn_mfma_f32_16x16x32_f16(
              af[mi], bf[ni], acc[mi][ni], 0, 0, 0);
    }
    asm volatile("s_waitcnt vmcnt(0)" ::: "memory");
    __syncthreads();
  }

#pragma unroll
  for (int mi = 0; mi < 2; ++mi) {
#pragma unroll
    for (int j = 0; j < 4; ++j) {
      int row = row0 + wm * 32 + mi * 16 + lg * 4 + j;
      if (row < nN) {
#pragma unroll
        for (int ni = 0; ni < 4; ++ni) {
          int col = wn * 64 + ni * 16 + lr;
          float v = acc[mi][ni][j];
          if (RELU) v = fmaxf(v, 0.f);
          if (F16OUT)
            ((_Float16*)outv)[(size_t)row * DD + col] = (_Float16)v;
          else
            ((float*)outv)[(size_t)row * DD + col] = v;
        }
      }
    }
  }
}

// ---------------- maskf scatter: maskf[mri[i]] = 1 ----------------
__global__ __launch_bounds__(256) void maskset_k(const int* __restrict__ mri,
    float* __restrict__ maskf, int nd) {
  int i = blockIdx.x * 256 + threadIdx.x;
  if (i < nd) maskf[mri[i]] = 1.0f;
}

// ---------------- gather disease rows (fp32 hbp) + scatter f16 into hbs ----
__global__ __launch_bounds__(256) void gather2_k(const float* __restrict__ h2,
    const int* __restrict__ bli, const int* __restrict__ mri,
    float* __restrict__ hbp, _Float16* __restrict__ hbs, int nd) {
  int gid = blockIdx.x * 256 + threadIdx.x;
  int i = gid >> 5, q = gid & 31;
  if (i < nd) {
    float4 v = *(const float4*)(h2 + (size_t)bli[i] * DD + q * 4);
    *(float4*)(hbp + (size_t)i * DD + q * 4) = v;
    h4 o = {(_Float16)v.x, (_Float16)v.y, (_Float16)v.z, (_Float16)v.w};
    *(h4*)(hbs + (size_t)mri[i] * DD + q * 4) = o;
  }
}

// ---------------- transpose hbs[KP][128] -> hbsT[128][KP] ----------------
__global__ __launch_bounds__(256) void transpose_k(const _Float16* __restrict__ hbs,
    _Float16* __restrict__ hbsT) {
  __shared__ _Float16 tile[64][72];
  int r0 = blockIdx.x * 64, c0 = blockIdx.y * 64;
  int t = threadIdx.x;
  int r = t >> 2, cs = (t & 3) * 16;
  *(h8*)&tile[r][cs]     = *(const h8*)(hbs + (size_t)(r0 + r) * DD + c0 + cs);
  *(h8*)&tile[r][cs + 8] = *(const h8*)(hbs + (size_t)(r0 + r) * DD + c0 + cs + 8);
  __syncthreads();
  int n = t >> 2, rs2 = (t & 3) * 16;
  h8 o0, o1;
#pragma unroll
  for (int j = 0; j < 8; ++j) {
    o0[j] = tile[rs2 + j][n];
    o1[j] = tile[rs2 + 8 + j][n];
  }
  *(h8*)(hbsT + (size_t)(c0 + n) * KP + r0 + rs2)     = o0;
  *(h8*)(hbsT + (size_t)(c0 + n) * KP + r0 + rs2 + 8) = o1;
}

// ---------------- sim MFMA GEMM: hs_part[ky] = simh[:, kchunk] @ hbsT^T ----
__global__ __launch_bounds__(256) void sim_mfma(const _Float16* __restrict__ simh,
    const _Float16* __restrict__ hbsT, float* __restrict__ hs_part, int nd) {
  __shared__ _Float16 Ab[2][64 * 64];
  __shared__ _Float16 Bb[2][128 * 64];
  const int t = threadIdx.x;
  const int lane = t & 63, w = t >> 6;
  const int row0 = blockIdx.x * 64;
  const int kb0 = blockIdx.y * (KP / KSPLIT);
  const int wm = w >> 1, wn = w & 1;
  const int lr = lane & 15, lg = lane >> 4;

  f4 acc[2][4];
#pragma unroll
  for (int mi = 0; mi < 2; ++mi)
#pragma unroll
    for (int ni = 0; ni < 4; ++ni) acc[mi][ni] = (f4){0.f, 0.f, 0.f, 0.f};

  const _Float16* pA[2];
  int ldsA[2];
#pragma unroll
  for (int j = 0; j < 2; ++j) {
    int q = j * 256 + w * 64 + lane;
    int row = q >> 3;
    int gck = (q & 7) ^ (row & 7);
    int m = row0 + row; if (m >= nd) m = nd - 1;
    pA[j] = simh + (size_t)m * KP + kb0 + gck * 8;
    ldsA[j] = (j * 256 + w * 64) * 8;
  }
  const _Float16* pB[4];
  int ldsB[4];
#pragma unroll
  for (int i = 0; i < 4; ++i) {
    int q = i * 256 + w * 64 + lane;
    int n = q >> 3;
    int gck = (q & 7) ^ (n & 7);
    pB[i] = hbsT + (size_t)n * KP + kb0 + gck * 8;
    ldsB[i] = (i * 256 + w * 64) * 8;
  }

  const int nsteps = (KP / KSPLIT) / 64;  // 8
#pragma unroll
  for (int j = 0; j < 2; ++j) gload16(pA[j], &Ab[0][ldsA[j]]);
#pragma unroll
  for (int i = 0; i < 4; ++i) gload16(pB[i], &Bb[0][ldsB[i]]);
  asm volatile("s_waitcnt vmcnt(0)" ::: "memory");
  __syncthreads();

  for (int ts = 0; ts < nsteps; ++ts) {
    const int cur = ts & 1;
    if (ts + 1 < nsteps) {
      const int kk = (ts + 1) * 64;
      const int nxt = cur ^ 1;
#pragma unroll
      for (int j = 0; j < 2; ++j) gload16(pA[j] + kk, &Ab[nxt][ldsA[j]]);
#pragma unroll
      for (int i = 0; i < 4; ++i) gload16(pB[i] + kk, &Bb[nxt][ldsB[i]]);
    }
#pragma unroll
    for (int s = 0; s < 2; ++s) {
      h8 af[2], bf[4];
#pragma unroll
      for (int mi = 0; mi < 2; ++mi) {
        int r = wm * 32 + mi * 16 + lr;
        af[mi] = *(const h8*)&Ab[cur][r * 64 + (((s * 4 + lg) ^ (r & 7)) << 3)];
      }
#pragma unroll
      for (int ni = 0; ni < 4; ++ni) {
        int n = wn * 64 + ni * 16 + lr;
        bf[ni] = *(const h8*)&Bb[cur][n * 64 + (((s * 4 + lg) ^ (n & 7)) << 3)];
      }
#pragma unroll
      for (int mi = 0; mi < 2; ++mi)
#pragma unroll
        for (int ni = 0; ni < 4; ++ni)
          acc[mi][ni] = __builtin_amdgcn_mfma_f32_16x16x32_f16(
              af[mi], bf[ni], acc[mi][ni], 0, 0, 0);
    }
    asm volatile("s_waitcnt vmcnt(0)" ::: "memory");
    __syncthreads();
  }

  float* dst = hs_part + (size_t)blockIdx.y * nd * DD;
#pragma unroll
  for (int mi = 0; mi < 2; ++mi) {
#pragma unroll
    for (int j = 0; j < 4; ++j) {
      int row = row0 + wm * 32 + mi * 16 + lg * 4 + j;
      if (row < nd) {
#pragma unroll
        for (int ni = 0; ni < 4; ++ni) {
          int col = wn * 64 + ni * 16 + lr;
          dst[(size_t)row * DD + col] = acc[mi][ni][j];
        }
      }
    }
  }
}

// ---------------- fused K-split reduce + final blend (deg from off) -------
__global__ __launch_bounds__(256) void reduce_final_k(
    const float* __restrict__ part, const float* __restrict__ hbp,
    const float* __restrict__ rs, const int* __restrict__ bli,
    const int* __restrict__ off, float* __restrict__ out, int nd,
    int NR, int E) {
  int gid = blockIdx.x * 256 + threadIdx.x;
  int i = gid >> 5, q = gid & 31;
  if (i < nd) {
    f4 s = (f4){0.f, 0.f, 0.f, 0.f};
#pragma unroll
    for (int p = 0; p < KSPLIT; ++p)
      s += *(const f4*)(part + (size_t)p * nd * DD + (size_t)i * DD + q * 4);
    int g = bli[i];
    int o0 = off[g * RR];
    int o1 = (g * RR + RR < NR) ? off[g * RR + RR] : E;
    float degf = (float)(o1 - o0);
    float cg = 0.7f * expf(-0.7f * degf) + 0.2f;
    float inv = 1.0f / rs[i];
    f4 bb = *(const f4*)(hbp + (size_t)i * DD + q * 4);
    f4 o;
#pragma unroll
    for (int j = 0; j < 4; ++j) o[j] = cg * (s[j] * inv) + (1.f - cg) * bb[j];
    *(f4*)(out + (size_t)g * DD + q * 4) = o;
  }
}

extern "C" void kernel_launch(void* const* d_in, const int* in_sizes, int n_in,
                              void* d_out, int out_size, void* d_ws, size_t ws_size,
                              hipStream_t stream) {
  const float* x   = (const float*)d_in[0];
  const float* sim = (const float*)d_in[1];
  const float* W1s = (const float*)d_in[2];
  const float* W1r = (const float*)d_in[3];
  const float* W2s = (const float*)d_in[4];
  const float* W2r = (const float*)d_in[5];
  const int* esrc  = (const int*)d_in[6];
  const int* edst  = (const int*)d_in[7];
  const int* etyp  = (const int*)d_in[8];
  const int* bli   = (const int*)d_in[9];
  const int* mri   = (const int*)d_in[10];
  const int N  = in_sizes[0] / DD;
  const int E  = in_sizes[6];
  const int ND = in_sizes[9];
  const int NR = N * RR;
  float* out = (float*)d_out;

  // workspace carve-up (~163 MB)
  char* w = (char*)d_ws;
  _Float16* msg  = (_Float16*)w; w += (size_t)NR * DD * sizeof(_Float16);   // 82 MB
  _Float16* xh   = (_Float16*)w; w += (size_t)N * DD * sizeof(_Float16);
  _Float16* h1h  = (_Float16*)w; w += (size_t)N * DD * sizeof(_Float16);
  _Float16* WT1  = (_Float16*)w; w += (size_t)DD * KK * sizeof(_Float16);
  _Float16* WT2  = (_Float16*)w; w += (size_t)DD * KK * sizeof(_Float16);
  _Float16* simh = (_Float16*)w; w += (size_t)ND * KP * sizeof(_Float16);
  _Float16* hbs  = (_Float16*)w; w += (size_t)KP * DD * sizeof(_Float16);
  _Float16* hbsT = (_Float16*)w; w += (size_t)DD * KP * sizeof(_Float16);
  float* hs_part = (float*)w; w += (size_t)KSPLIT * ND * DD * sizeof(float);
  float* hbp   = (float*)w; w += (size_t)ND * DD * sizeof(float);
  float* maskf = (float*)w; w += (size_t)KP * sizeof(float);
  int* cnt  = (int*)w; w += (size_t)NR * sizeof(int);
  int* off  = (int*)w; w += (size_t)NR * sizeof(int);
  int* cur  = (int*)w; w += (size_t)NR * sizeof(int);
  int* eidx = (int*)w; w += (size_t)E * sizeof(int);
  int* bsum = (int*)w; w += 1024 * sizeof(int);
  float* rs = (float*)w; w += (size_t)ND * sizeof(float);

  // ---- CSR build (deg atomics eliminated; deg derived from off) ----
  hipMemsetAsync(cnt, 0, (size_t)NR * sizeof(int), stream);
  count_k<<<(E + 255) / 256, 256, 0, stream>>>(edst, etyp, cnt, E);
  int nblk = (NR + SCAN_CHUNK - 1) / SCAN_CHUNK;
  scan_a<<<nblk, 256, 0, stream>>>(cnt, off, bsum, NR);
  scan_b<<<1, 256, 0, stream>>>(bsum, nblk);
  scan_c<<<(NR + 255) / 256, 256, 0, stream>>>(off, bsum, NR);
  hipMemcpyAsync(cur, off, (size_t)NR * sizeof(int), hipMemcpyDeviceToDevice, stream);
  fill_k<<<(E + 255) / 256, 256, 0, stream>>>(esrc, edst, etyp, cur, eidx, E);

  // ---- f16 conversions + sim mask prep + hbs clear (all independent) ----
  convx_k<<<(N * DD / 4 + 255) / 256, 256, 0, stream>>>(x, xh, N * DD / 4);
  dim3 wgrid(KK / 64, DD / 64);
  convwT_k<<<wgrid, 256, 0, stream>>>(W1s, W1r, WT1);
  convwT_k<<<wgrid, 256, 0, stream>>>(W2s, W2r, WT2);
  hipMemsetAsync(maskf, 0, (size_t)KP * sizeof(float), stream);
  maskset_k<<<(ND + 255) / 256, 256, 0, stream>>>(mri, maskf, ND);
  hipMemsetAsync(hbs, 0, (size_t)KP * DD * sizeof(_Float16), stream);

  // ---- layer 1 aggregation co-scheduled with convsim ----
  int aggBlk = (NR * 16 + 255) / 256;
  agg1_convsim_k<<<ND + aggBlk, 256, 0, stream>>>(
      xh, off, eidx, msg, NR, E, sim, mri, maskf, simh, rs, ND);
  rgcn_mfma<true, true><<<(N + 63) / 64, 256, 0, stream>>>(xh, msg, WT1, h1h, N);

  // ---- layer 2 ----
  agg_k<<<aggBlk, 256, 0, stream>>>(h1h, off, eidx, msg, NR, E);
  rgcn_mfma<false, false><<<(N + 63) / 64, 256, 0, stream>>>(h1h, msg, WT2, out, N);

  // ---- similarity diffusion ----
  gather2_k<<<(ND * 32 + 255) / 256, 256, 0, stream>>>(out, bli, mri, hbp, hbs, ND);
  dim3 tgrid(KP / 64, DD / 64);
  transpose_k<<<tgrid, 256, 0, stream>>>(hbs, hbsT);
  dim3 sgrid((ND + 63) / 64, KSPLIT);
  sim_mfma<<<sgrid, 256, 0, stream>>>(simh, hbsT, hs_part, ND);
  reduce_final_k<<<(ND * 32 + 255) / 256, 256, 0, stream>>>(
      hs_part, hbp, rs, bli, off, out, ND, NR, E);
}

// Round 11
// 252.812 us; speedup vs baseline: 2.3847x; 1.0537x over previous
//
#include <hip/hip_runtime.h>
#include <hip/hip_bf16.h>

#define DD 128
#define RR 8
#define KK 1152      // RGCN composite K = 128 + 8*128
#define SCAN_CHUNK 2048
#define KSPLIT 8
#define KP 4096      // padded sim K

typedef _Float16 h8 __attribute__((ext_vector_type(8)));
typedef _Float16 h4 __attribute__((ext_vector_type(4)));
typedef float f4 __attribute__((ext_vector_type(4)));

__device__ __forceinline__ void gload16(const _Float16* g, _Float16* l) {
  __builtin_amdgcn_global_load_lds(
      (const __attribute__((address_space(1))) void*)g,
      (__attribute__((address_space(3))) void*)l, 16, 0, 0);
}

// ---------------- 3-phase exclusive scan of cnt -> off ----------------
__global__ __launch_bounds__(256) void scan_a(const int* __restrict__ cnt,
    int* __restrict__ off, int* __restrict__ bsum, int n) {
  __shared__ int red[256];
  int base = blockIdx.x * SCAN_CHUNK + threadIdx.x * 8;
  int v[8];
  int s = 0;
#pragma unroll
  for (int i = 0; i < 8; ++i) {
    int idx = base + i;
    v[i] = s;
    s += (idx < n) ? cnt[idx] : 0;
  }
  red[threadIdx.x] = s;
  __syncthreads();
  for (int o = 1; o < 256; o <<= 1) {
    int t = (threadIdx.x >= o) ? red[threadIdx.x - o] : 0;
    __syncthreads();
    red[threadIdx.x] += t;
    __syncthreads();
  }
  int pre = (threadIdx.x > 0) ? red[threadIdx.x - 1] : 0;
#pragma unroll
  for (int i = 0; i < 8; ++i) {
    int idx = base + i;
    if (idx < n) off[idx] = v[i] + pre;
  }
  if (threadIdx.x == 255) bsum[blockIdx.x] = red[255];
}

__global__ void scan_b(int* __restrict__ bsum, int nb) {
  if (threadIdx.x == 0) {
    int s = 0;
    for (int i = 0; i < nb; ++i) { int t = bsum[i]; bsum[i] = s; s += t; }
  }
}

// scan_c also materializes cur (= off copy) -> deletes the d2d memcpy
__global__ __launch_bounds__(256) void scan_c(int* __restrict__ off,
    const int* __restrict__ bsum, int* __restrict__ cur, int n) {
  int i = blockIdx.x * 256 + threadIdx.x;
  if (i < n) {
    int v = off[i] + bsum[i >> 11];
    off[i] = v;
    cur[i] = v;
  }
}

// ---------------- fill CSR ----------------
__global__ __launch_bounds__(256) void fill_k(const int* __restrict__ esrc,
    const int* __restrict__ edst, const int* __restrict__ etyp,
    int* __restrict__ cur, int* __restrict__ eidx, int E) {
  int e = blockIdx.x * 256 + threadIdx.x;
  if (e < E) {
    int seg = edst[e] * RR + etyp[e];
    int p = atomicAdd(&cur[seg], 1);
    eidx[p] = esrc[e];
  }
}

// ---------------- maskf scatter: maskf[mri[i]] = 1 ----------------
__global__ __launch_bounds__(256) void maskset_k(const int* __restrict__ mri,
    float* __restrict__ maskf, int nd) {
  int i = blockIdx.x * 256 + threadIdx.x;
  if (i < nd) maskf[mri[i]] = 1.0f;
}

// ---------------- sim row convert + fused rowsum (body) ----------------
__device__ __forceinline__ void convsim_body(const float* __restrict__ sim,
    const int* __restrict__ mri, const float* __restrict__ maskf,
    _Float16* __restrict__ simh, float* __restrict__ rs, int nd, int i,
    float* red) {
  const float* row = sim + (size_t)mri[i] * nd;
  float acc = 0.f;
  for (int c4 = threadIdx.x; c4 < KP / 4; c4 += 256) {
    int c = c4 * 4;
    float4 v = make_float4(0.f, 0.f, 0.f, 0.f);
    if (c < nd) {
      v = *(const float4*)(row + c);
      float4 mk = *(const float4*)(maskf + c);
      acc += v.x * mk.x + v.y * mk.y + v.z * mk.z + v.w * mk.w;
    }
    h4 o = {(_Float16)v.x, (_Float16)v.y, (_Float16)v.z, (_Float16)v.w};
    *(h4*)(simh + (size_t)i * KP + c) = o;
  }
  red[threadIdx.x] = acc;
  __syncthreads();
  for (int o = 128; o > 0; o >>= 1) {
    if (threadIdx.x < o) red[threadIdx.x] += red[threadIdx.x + o];
    __syncthreads();
  }
  if (threadIdx.x == 0) rs[i] = red[0] + 1e-9f;
}

// ---------------- transposed f16 weights via LDS tile (body) ----------------
__device__ __forceinline__ void convwT_body(const float* __restrict__ Ws,
    const float* __restrict__ Wr, _Float16* __restrict__ WT, int bid,
    _Float16 (*tile)[72]) {
  const int k0 = (bid % (KK / 64)) * 64, n0 = (bid / (KK / 64)) * 64;
  const int t = threadIdx.x;
  {
    int kr = t >> 2, c0 = (t & 3) * 16;
    int k = k0 + kr;
    const float* src = (k < DD) ? (Ws + (size_t)k * DD + n0 + c0)
                                : (Wr + (size_t)(k - DD) * DD + n0 + c0);
#pragma unroll
    for (int j = 0; j < 16; j += 4) {
      float4 v = *(const float4*)(src + j);
      tile[kr][c0 + j + 0] = (_Float16)v.x;
      tile[kr][c0 + j + 1] = (_Float16)v.y;
      tile[kr][c0 + j + 2] = (_Float16)v.z;
      tile[kr][c0 + j + 3] = (_Float16)v.w;
    }
  }
  __syncthreads();
  {
    int nr = t >> 2, ck = (t & 3) * 16;
    h8 o0, o1;
#pragma unroll
    for (int j = 0; j < 8; ++j) {
      o0[j] = tile[ck + j][nr];
      o1[j] = tile[ck + 8 + j][nr];
    }
    *(h8*)(WT + (size_t)(n0 + nr) * KK + k0 + ck) = o0;
    *(h8*)(WT + (size_t)(n0 + nr) * KK + k0 + ck + 8) = o1;
  }
}

// ---------------- mega prep: convsim | convx | convwT x2 | count ----------
// All roles mutually independent; convsim streaming hides count's atomic
// latency and vice versa.
__global__ __launch_bounds__(256) void prep_k(
    const float* __restrict__ sim, const int* __restrict__ mri,
    const float* __restrict__ maskf, _Float16* __restrict__ simh,
    float* __restrict__ rs, int nd,
    const float* __restrict__ x, _Float16* __restrict__ xh, int n4x,
    const float* __restrict__ W1s, const float* __restrict__ W1r,
    _Float16* __restrict__ WT1,
    const float* __restrict__ W2s, const float* __restrict__ W2r,
    _Float16* __restrict__ WT2,
    const int* __restrict__ edst, const int* __restrict__ etyp,
    int* __restrict__ cnt, int E, int bX, int bW) {
  __shared__ char smem[64 * 72 * 2];  // convwT tile / convsim reduction
  const int b = blockIdx.x, t = threadIdx.x;
  if (b < nd) {
    convsim_body(sim, mri, maskf, simh, rs, nd, b, (float*)smem);
    return;
  }
  int b2 = b - nd;
  if (b2 < bX) {
    int i = b2 * 256 + t;
    if (i < n4x) {
      float4 v = *(const float4*)(x + (size_t)i * 4);
      h4 o = {(_Float16)v.x, (_Float16)v.y, (_Float16)v.z, (_Float16)v.w};
      *(h4*)(xh + (size_t)i * 4) = o;
    }
    return;
  }
  b2 -= bX;
  if (b2 < bW) {
    convwT_body(W1s, W1r, WT1, b2, (_Float16(*)[72])smem);
    return;
  }
  b2 -= bW;
  if (b2 < bW) {
    convwT_body(W2s, W2r, WT2, b2, (_Float16(*)[72])smem);
    return;
  }
  b2 -= bW;
  {
    int i = b2 * 256 + t;
    if (i < E) atomicAdd(&cnt[edst[i] * RR + etyp[i]], 1);
  }
}

// ---------------- aggregation: 16 lanes/seg, h8 loads, 4-deep pipeline ----
__device__ __forceinline__ void agg_body(const _Float16* __restrict__ h,
    const int* __restrict__ off, const int* __restrict__ eidx,
    _Float16* __restrict__ msg, int nseg, int E, int gid) {
  int seg = gid >> 4, q = gid & 15;
  if (seg >= nseg) return;
  int b = off[seg];
  int e = (seg + 1 < nseg) ? off[seg + 1] : E;
  int n = e - b;
  float a[8];
#pragma unroll
  for (int j = 0; j < 8; ++j) a[j] = 0.f;
  if (n > 0) {
    int e1 = e - 1;
    int s0 = eidx[b];
    int s1 = eidx[min(b + 1, e1)];
    int s2 = eidx[min(b + 2, e1)];
    int s3 = eidx[min(b + 3, e1)];
    h8 v0 = *(const h8*)(h + (size_t)s0 * DD + q * 8);
    h8 v1 = *(const h8*)(h + (size_t)s1 * DD + q * 8);
    h8 v2 = *(const h8*)(h + (size_t)s2 * DD + q * 8);
    h8 v3 = *(const h8*)(h + (size_t)s3 * DD + q * 8);
#pragma unroll
    for (int j = 0; j < 8; ++j) a[j] = (float)v0[j];
    if (n > 1) {
#pragma unroll
      for (int j = 0; j < 8; ++j) a[j] += (float)v1[j];
    }
    if (n > 2) {
#pragma unroll
      for (int j = 0; j < 8; ++j) a[j] += (float)v2[j];
    }
    if (n > 3) {
#pragma unroll
      for (int j = 0; j < 8; ++j) a[j] += (float)v3[j];
    }
    for (int i = b + 4; i < e; ++i) {  // rare tail
      int s = eidx[i];
      h8 v = *(const h8*)(h + (size_t)s * DD + q * 8);
#pragma unroll
      for (int j = 0; j < 8; ++j) a[j] += (float)v[j];
    }
  }
  float ic = (n > 0) ? 1.0f / (float)n : 0.0f;
  h8 o;
#pragma unroll
  for (int j = 0; j < 8; ++j) o[j] = (_Float16)(a[j] * ic);
  *(h8*)(msg + (size_t)seg * DD + q * 8) = o;
}

__global__ __launch_bounds__(256) void agg_k(const _Float16* __restrict__ h,
    const int* __restrict__ off, const int* __restrict__ eidx,
    _Float16* __restrict__ msg, int nseg, int E) {
  agg_body(h, off, eidx, msg, nseg, E, blockIdx.x * 256 + threadIdx.x);
}

// ---------------- MFMA RGCN GEMM: out = [xh | msg] @ WT^T ----------------
template <bool RELU, bool F16OUT>
__global__ __launch_bounds__(256) void rgcn_mfma(const _Float16* __restrict__ xh,
    const _Float16* __restrict__ msg, const _Float16* __restrict__ WT,
    void* __restrict__ outv, int nN) {
  __shared__ _Float16 Ab[2][64 * 64];
  __shared__ _Float16 Bb[2][128 * 64];
  const int t = threadIdx.x;
  const int lane = t & 63, w = t >> 6;
  const int row0 = blockIdx.x * 64;
  const int wm = w >> 1, wn = w & 1;
  const int lr = lane & 15, lg = lane >> 4;

  f4 acc[2][4];
#pragma unroll
  for (int mi = 0; mi < 2; ++mi)
#pragma unroll
    for (int ni = 0; ni < 4; ++ni) acc[mi][ni] = (f4){0.f, 0.f, 0.f, 0.f};

  const _Float16* pxh[2];
  const _Float16* pmsg[2];
  int ldsA[2];
#pragma unroll
  for (int j = 0; j < 2; ++j) {
    int q = j * 256 + w * 64 + lane;
    int row = q >> 3;
    int gck = (q & 7) ^ (row & 7);
    int m = row0 + row; if (m >= nN) m = nN - 1;
    pxh[j] = xh + (size_t)m * DD + gck * 8;
    pmsg[j] = msg + (size_t)m * (RR * DD) + gck * 8;
    ldsA[j] = (j * 256 + w * 64) * 8;
  }
  const _Float16* pB[4];
  int ldsB[4];
#pragma unroll
  for (int i = 0; i < 4; ++i) {
    int q = i * 256 + w * 64 + lane;
    int n = q >> 3;
    int gck = (q & 7) ^ (n & 7);
    pB[i] = WT + (size_t)n * KK + gck * 8;
    ldsB[i] = (i * 256 + w * 64) * 8;
  }

  const int nsteps = KK / 64;  // 18
#pragma unroll
  for (int j = 0; j < 2; ++j) gload16(pxh[j], &Ab[0][ldsA[j]]);
#pragma unroll
  for (int i = 0; i < 4; ++i) gload16(pB[i], &Bb[0][ldsB[i]]);
  asm volatile("s_waitcnt vmcnt(0)" ::: "memory");
  __syncthreads();

  for (int ts = 0; ts < nsteps; ++ts) {
    const int cur = ts & 1;
    if (ts + 1 < nsteps) {
      const int kk = (ts + 1) * 64;
      const int nxt = cur ^ 1;
      if (kk < DD) {
#pragma unroll
        for (int j = 0; j < 2; ++j) gload16(pxh[j] + kk, &Ab[nxt][ldsA[j]]);
      } else {
#pragma unroll
        for (int j = 0; j < 2; ++j) gload16(pmsg[j] + (kk - DD), &Ab[nxt][ldsA[j]]);
      }
#pragma unroll
      for (int i = 0; i < 4; ++i) gload16(pB[i] + kk, &Bb[nxt][ldsB[i]]);
    }
#pragma unroll
    for (int s = 0; s < 2; ++s) {
      h8 af[2], bf[4];
#pragma unroll
      for (int mi = 0; mi < 2; ++mi) {
        int r = wm * 32 + mi * 16 + lr;
        af[mi] = *(const h8*)&Ab[cur][r * 64 + (((s * 4 + lg) ^ (r & 7)) << 3)];
      }
#pragma unroll
      for (int ni = 0; ni < 4; ++ni) {
        int n = wn * 64 + ni * 16 + lr;
        bf[ni] = *(const h8*)&Bb[cur][n * 64 + (((s * 4 + lg) ^ (n & 7)) << 3)];
      }
#pragma unroll
      for (int mi = 0; mi < 2; ++mi)
#pragma unroll
        for (int ni = 0; ni < 4; ++ni)
          acc[mi][ni] = __builtin_amdgcn_mfma_f32_16x16x32_f16(
              af[mi], bf[ni], acc[mi][ni], 0, 0, 0);
    }
    asm volatile("s_waitcnt vmcnt(0)" ::: "memory");
    __syncthreads();
  }

#pragma unroll
  for (int mi = 0; mi < 2; ++mi) {
#pragma unroll
    for (int j = 0; j < 4; ++j) {
      int row = row0 + wm * 32 + mi * 16 + lg * 4 + j;
      if (row < nN) {
#pragma unroll
        for (int ni = 0; ni < 4; ++ni) {
          int col = wn * 64 + ni * 16 + lr;
          float v = acc[mi][ni][j];
          if (RELU) v = fmaxf(v, 0.f);
          if (F16OUT)
            ((_Float16*)outv)[(size_t)row * DD + col] = (_Float16)v;
          else
            ((float*)outv)[(size_t)row * DD + col] = v;
        }
      }
    }
  }
}

// ---------------- gather disease rows (fp32 hbp) + scatter f16 into hbs ----
__global__ __launch_bounds__(256) void gather2_k(const float* __restrict__ h2,
    const int* __restrict__ bli, const int* __restrict__ mri,
    float* __restrict__ hbp, _Float16* __restrict__ hbs, int nd) {
  int gid = blockIdx.x * 256 + threadIdx.x;
  int i = gid >> 5, q = gid & 31;
  if (i < nd) {
    float4 v = *(const float4*)(h2 + (size_t)bli[i] * DD + q * 4);
    *(float4*)(hbp + (size_t)i * DD + q * 4) = v;
    h4 o = {(_Float16)v.x, (_Float16)v.y, (_Float16)v.z, (_Float16)v.w};
    *(h4*)(hbs + (size_t)mri[i] * DD + q * 4) = o;
  }
}

// ---------------- transpose hbs[KP][128] -> hbsT[128][KP] ----------------
__global__ __launch_bounds__(256) void transpose_k(const _Float16* __restrict__ hbs,
    _Float16* __restrict__ hbsT) {
  __shared__ _Float16 tile[64][72];
  int r0 = blockIdx.x * 64, c0 = blockIdx.y * 64;
  int t = threadIdx.x;
  int r = t >> 2, cs = (t & 3) * 16;
  *(h8*)&tile[r][cs]     = *(const h8*)(hbs + (size_t)(r0 + r) * DD + c0 + cs);
  *(h8*)&tile[r][cs + 8] = *(const h8*)(hbs + (size_t)(r0 + r) * DD + c0 + cs + 8);
  __syncthreads();
  int n = t >> 2, rs2 = (t & 3) * 16;
  h8 o0, o1;
#pragma unroll
  for (int j = 0; j < 8; ++j) {
    o0[j] = tile[rs2 + j][n];
    o1[j] = tile[rs2 + 8 + j][n];
  }
  *(h8*)(hbsT + (size_t)(c0 + n) * KP + r0 + rs2)     = o0;
  *(h8*)(hbsT + (size_t)(c0 + n) * KP + r0 + rs2 + 8) = o1;
}

// ---------------- sim MFMA GEMM: hs_part[ky] = simh[:, kchunk] @ hbsT^T ----
__global__ __launch_bounds__(256) void sim_mfma(const _Float16* __restrict__ simh,
    const _Float16* __restrict__ hbsT, float* __restrict__ hs_part, int nd) {
  __shared__ _Float16 Ab[2][64 * 64];
  __shared__ _Float16 Bb[2][128 * 64];
  const int t = threadIdx.x;
  const int lane = t & 63, w = t >> 6;
  const int row0 = blockIdx.x * 64;
  const int kb0 = blockIdx.y * (KP / KSPLIT);
  const int wm = w >> 1, wn = w & 1;
  const int lr = lane & 15, lg = lane >> 4;

  f4 acc[2][4];
#pragma unroll
  for (int mi = 0; mi < 2; ++mi)
#pragma unroll
    for (int ni = 0; ni < 4; ++ni) acc[mi][ni] = (f4){0.f, 0.f, 0.f, 0.f};

  const _Float16* pA[2];
  int ldsA[2];
#pragma unroll
  for (int j = 0; j < 2; ++j) {
    int q = j * 256 + w * 64 + lane;
    int row = q >> 3;
    int gck = (q & 7) ^ (row & 7);
    int m = row0 + row; if (m >= nd) m = nd - 1;
    pA[j] = simh + (size_t)m * KP + kb0 + gck * 8;
    ldsA[j] = (j * 256 + w * 64) * 8;
  }
  const _Float16* pB[4];
  int ldsB[4];
#pragma unroll
  for (int i = 0; i < 4; ++i) {
    int q = i * 256 + w * 64 + lane;
    int n = q >> 3;
    int gck = (q & 7) ^ (n & 7);
    pB[i] = hbsT + (size_t)n * KP + kb0 + gck * 8;
    ldsB[i] = (i * 256 + w * 64) * 8;
  }

  const int nsteps = (KP / KSPLIT) / 64;  // 8
#pragma unroll
  for (int j = 0; j < 2; ++j) gload16(pA[j], &Ab[0][ldsA[j]]);
#pragma unroll
  for (int i = 0; i < 4; ++i) gload16(pB[i], &Bb[0][ldsB[i]]);
  asm volatile("s_waitcnt vmcnt(0)" ::: "memory");
  __syncthreads();

  for (int ts = 0; ts < nsteps; ++ts) {
    const int cur = ts & 1;
    if (ts + 1 < nsteps) {
      const int kk = (ts + 1) * 64;
      const int nxt = cur ^ 1;
#pragma unroll
      for (int j = 0; j < 2; ++j) gload16(pA[j] + kk, &Ab[nxt][ldsA[j]]);
#pragma unroll
      for (int i = 0; i < 4; ++i) gload16(pB[i] + kk, &Bb[nxt][ldsB[i]]);
    }
#pragma unroll
    for (int s = 0; s < 2; ++s) {
      h8 af[2], bf[4];
#pragma unroll
      for (int mi = 0; mi < 2; ++mi) {
        int r = wm * 32 + mi * 16 + lr;
        af[mi] = *(const h8*)&Ab[cur][r * 64 + (((s * 4 + lg) ^ (r & 7)) << 3)];
      }
#pragma unroll
      for (int ni = 0; ni < 4; ++ni) {
        int n = wn * 64 + ni * 16 + lr;
        bf[ni] = *(const h8*)&Bb[cur][n * 64 + (((s * 4 + lg) ^ (n & 7)) << 3)];
      }
#pragma unroll
      for (int mi = 0; mi < 2; ++mi)
#pragma unroll
        for (int ni = 0; ni < 4; ++ni)
          acc[mi][ni] = __builtin_amdgcn_mfma_f32_16x16x32_f16(
              af[mi], bf[ni], acc[mi][ni], 0, 0, 0);
    }
    asm volatile("s_waitcnt vmcnt(0)" ::: "memory");
    __syncthreads();
  }

  float* dst = hs_part + (size_t)blockIdx.y * nd * DD;
#pragma unroll
  for (int mi = 0; mi < 2; ++mi) {
#pragma unroll
    for (int j = 0; j < 4; ++j) {
      int row = row0 + wm * 32 + mi * 16 + lg * 4 + j;
      if (row < nd) {
#pragma unroll
        for (int ni = 0; ni < 4; ++ni) {
          int col = wn * 64 + ni * 16 + lr;
          dst[(size_t)row * DD + col] = acc[mi][ni][j];
        }
      }
    }
  }
}

// ---------------- fused K-split reduce + final blend (deg from off) -------
__global__ __launch_bounds__(256) void reduce_final_k(
    const float* __restrict__ part, const float* __restrict__ hbp,
    const float* __restrict__ rs, const int* __restrict__ bli,
    const int* __restrict__ off, float* __restrict__ out, int nd,
    int NR, int E) {
  int gid = blockIdx.x * 256 + threadIdx.x;
  int i = gid >> 5, q = gid & 31;
  if (i < nd) {
    f4 s = (f4){0.f, 0.f, 0.f, 0.f};
#pragma unroll
    for (int p = 0; p < KSPLIT; ++p)
      s += *(const f4*)(part + (size_t)p * nd * DD + (size_t)i * DD + q * 4);
    int g = bli[i];
    int o0 = off[g * RR];
    int o1 = (g * RR + RR < NR) ? off[g * RR + RR] : E;
    float degf = (float)(o1 - o0);
    float cg = 0.7f * expf(-0.7f * degf) + 0.2f;
    float inv = 1.0f / rs[i];
    f4 bb = *(const f4*)(hbp + (size_t)i * DD + q * 4);
    f4 o;
#pragma unroll
    for (int j = 0; j < 4; ++j) o[j] = cg * (s[j] * inv) + (1.f - cg) * bb[j];
    *(f4*)(out + (size_t)g * DD + q * 4) = o;
  }
}

extern "C" void kernel_launch(void* const* d_in, const int* in_sizes, int n_in,
                              void* d_out, int out_size, void* d_ws, size_t ws_size,
                              hipStream_t stream) {
  const float* x   = (const float*)d_in[0];
  const float* sim = (const float*)d_in[1];
  const float* W1s = (const float*)d_in[2];
  const float* W1r = (const float*)d_in[3];
  const float* W2s = (const float*)d_in[4];
  const float* W2r = (const float*)d_in[5];
  const int* esrc  = (const int*)d_in[6];
  const int* edst  = (const int*)d_in[7];
  const int* etyp  = (const int*)d_in[8];
  const int* bli   = (const int*)d_in[9];
  const int* mri   = (const int*)d_in[10];
  const int N  = in_sizes[0] / DD;
  const int E  = in_sizes[6];
  const int ND = in_sizes[9];
  const int NR = N * RR;
  float* out = (float*)d_out;

  // workspace carve-up (~163 MB); cnt|maskf|hbs contiguous -> single memset
  char* w = (char*)d_ws;
  _Float16* msg  = (_Float16*)w; w += (size_t)NR * DD * sizeof(_Float16);   // 82 MB
  _Float16* xh   = (_Float16*)w; w += (size_t)N * DD * sizeof(_Float16);
  _Float16* h1h  = (_Float16*)w; w += (size_t)N * DD * sizeof(_Float16);
  _Float16* WT1  = (_Float16*)w; w += (size_t)DD * KK * sizeof(_Float16);
  _Float16* WT2  = (_Float16*)w; w += (size_t)DD * KK * sizeof(_Float16);
  _Float16* simh = (_Float16*)w; w += (size_t)ND * KP * sizeof(_Float16);
  _Float16* hbsT = (_Float16*)w; w += (size_t)DD * KP * sizeof(_Float16);
  float* hs_part = (float*)w; w += (size_t)KSPLIT * ND * DD * sizeof(float);
  float* hbp   = (float*)w; w += (size_t)ND * DD * sizeof(float);
  // ---- contiguous zero-init region ----
  int* cnt       = (int*)w;      w += (size_t)NR * sizeof(int);
  float* maskf   = (float*)w;    w += (size_t)KP * sizeof(float);
  _Float16* hbs  = (_Float16*)w; w += (size_t)KP * DD * sizeof(_Float16);
  // ----
  int* off  = (int*)w; w += (size_t)NR * sizeof(int);
  int* cur  = (int*)w; w += (size_t)NR * sizeof(int);
  int* eidx = (int*)w; w += (size_t)E * sizeof(int);
  int* bsum = (int*)w; w += 1024 * sizeof(int);
  float* rs = (float*)w; w += (size_t)ND * sizeof(float);

  const size_t zbytes = (size_t)NR * sizeof(int) + (size_t)KP * sizeof(float) +
                        (size_t)KP * DD * sizeof(_Float16);
  hipMemsetAsync(cnt, 0, zbytes, stream);
  maskset_k<<<(ND + 255) / 256, 256, 0, stream>>>(mri, maskf, ND);

  // ---- mega prep: convsim | convx | convwT x2 | count ----
  const int n4x = N * DD / 4;
  const int bX = (n4x + 255) / 256;
  const int bW = (KK / 64) * (DD / 64);  // 36
  const int bC = (E + 255) / 256;
  prep_k<<<ND + bX + 2 * bW + bC, 256, 0, stream>>>(
      sim, mri, maskf, simh, rs, ND, x, xh, n4x,
      W1s, W1r, WT1, W2s, W2r, WT2, edst, etyp, cnt, E, bX, bW);

  // ---- CSR scan + fill (scan_c also writes cur) ----
  int nblk = (NR + SCAN_CHUNK - 1) / SCAN_CHUNK;
  scan_a<<<nblk, 256, 0, stream>>>(cnt, off, bsum, NR);
  scan_b<<<1, 256, 0, stream>>>(bsum, nblk);
  scan_c<<<(NR + 255) / 256, 256, 0, stream>>>(off, bsum, cur, NR);
  fill_k<<<bC, 256, 0, stream>>>(esrc, edst, etyp, cur, eidx, E);

  // ---- layer 1 ----
  int aggBlk = (NR * 16 + 255) / 256;
  agg_k<<<aggBlk, 256, 0, stream>>>(xh, off, eidx, msg, NR, E);
  rgcn_mfma<true, true><<<(N + 63) / 64, 256, 0, stream>>>(xh, msg, WT1, h1h, N);

  // ---- layer 2 ----
  agg_k<<<aggBlk, 256, 0, stream>>>(h1h, off, eidx, msg, NR, E);
  rgcn_mfma<false, false><<<(N + 63) / 64, 256, 0, stream>>>(h1h, msg, WT2, out, N);

  // ---- similarity diffusion ----
  gather2_k<<<(ND * 32 + 255) / 256, 256, 0, stream>>>(out, bli, mri, hbp, hbs, ND);
  dim3 tgrid(KP / 64, DD / 64);
  transpose_k<<<tgrid, 256, 0, stream>>>(hbs, hbsT);
  dim3 sgrid((ND + 63) / 64, KSPLIT);
  sim_mfma<<<sgrid, 256, 0, stream>>>(simh, hbsT, hs_part, ND);
  reduce_final_k<<<(ND * 32 + 255) / 256, 256, 0, stream>>>(
      hs_part, hbp, rs, bli, off, out, ND, NR, E);
}